// Round 9
// baseline (1576.006 us; speedup 1.0000x reference)
//
#include <hip/hip_runtime.h>
#include <hip/hip_bf16.h>

#define B_ 2
#define S_ 2048
#define V_ 1024
#define D_ 512
#define H_ 8
#define L_ 6
#define DFF_ 2048
#define DK_ 64
#define MROWS (B_*S_)   // 4096
#define NEGINF (-__builtin_inff())

typedef __hip_bfloat16 bf16;
typedef __bf16 bf16x8 __attribute__((ext_vector_type(8)));
typedef float f32x4 __attribute__((ext_vector_type(4)));
typedef unsigned short us8 __attribute__((ext_vector_type(8)));
typedef unsigned short us4 __attribute__((ext_vector_type(4)));

__device__ __forceinline__ float bf2f(unsigned short u) {
    return __uint_as_float(((unsigned int)u) << 16);
}
// fp32 -> bf16 round-to-nearest-even
__device__ __forceinline__ unsigned short f2b(float x) {
    unsigned int u = __float_as_uint(x);
    return (unsigned short)((u + 0x7FFFu + ((u >> 16) & 1u)) >> 16);
}
// load element i of a float input that may be fp32 or bf16 (runtime flag bf)
__device__ __forceinline__ float ldin(const void* p, size_t i, int bf) {
    return bf ? bf2f(((const unsigned short*)p)[i]) : ((const float*)p)[i];
}

// ---------------- dtype detector: ln1_w is all ones ----------------
__global__ void detect_kernel(const unsigned int* __restrict__ w, int* __restrict__ flag) {
    if (threadIdx.x == 0) flag[0] = (w[0] == 0x3F800000u) ? 0 : 1;
}

// ---------------- embedding + positional encoding (fp32 out) ----------------
__global__ __launch_bounds__(256) void embed_kernel(const int* __restrict__ ids,
        const void* __restrict__ emb, float* __restrict__ x, const int* __restrict__ dtf)
{
    const int bf = dtf[0];
    int tid = blockIdx.x * 256 + threadIdx.x;   // over B*S*D
    int d = tid % D_;
    int bs = tid / D_;
    int s = bs % S_;
    int id = ids[bs];
    float e = ldin(emb, (size_t)id * D_ + d, bf);
    int i2 = d & ~1;
    float div = expf((float)i2 * (-9.210340371976184f / (float)D_)); // -ln(10000)/D
    float ang = (float)s * div;
    float pe = (d & 1) ? cosf(ang) : sinf(ang);
    x[tid] = e + pe;
}

// ---------------- layernorm: fp32 in, bf16 out (r6-998 proven config) ----------------
__global__ __launch_bounds__(256) void ln_kernel(const float* __restrict__ x,
        const void* __restrict__ w, const void* __restrict__ b, size_t off,
        unsigned short* __restrict__ out, const int* __restrict__ dtf)
{
    const int bf = dtf[0];
    __shared__ float red[256];
    const int row = blockIdx.x;
    const int tid = threadIdx.x;
    const float* xr = x + (size_t)row * D_;
    float v0 = xr[tid], v1 = xr[tid + 256];
    red[tid] = v0 + v1; __syncthreads();
    for (int s = 128; s > 0; s >>= 1) { if (tid < s) red[tid] += red[tid + s]; __syncthreads(); }
    float mu = red[0] * (1.f / D_); __syncthreads();
    float d0 = v0 - mu, d1 = v1 - mu;
    red[tid] = d0 * d0 + d1 * d1; __syncthreads();
    for (int s = 128; s > 0; s >>= 1) { if (tid < s) red[tid] += red[tid + s]; __syncthreads(); }
    float var = red[0] * (1.f / D_);
    float rstd = rsqrtf(var + 1e-5f);
    unsigned short* orow = out + (size_t)row * D_;
    orow[tid]       = f2b(d0 * rstd * ldin(w, off + tid, bf)       + ldin(b, off + tid, bf));
    orow[tid + 256] = f2b(d1 * rstd * ldin(w, off + tid + 256, bf) + ldin(b, off + tid + 256, bf));
}

// ---------------- weight transpose: W[K][N] -> Wt[N][K] bf16, 64x64 LDS tile ----------------
__device__ __forceinline__ void tr_tile(const void* src, size_t off, int K, int N,
        unsigned short* dst, int k0, int n0, int bf, unsigned short (*T)[72])
{
    const int t = threadIdx.x;
    const int r = t >> 2, c = (t & 3) * 16;
    size_t e = off + (size_t)(k0 + r) * N + n0 + c;
    us8 u0, u1;
    if (bf) {
        u0 = *(const us8*)((const unsigned short*)src + e);
        u1 = *(const us8*)((const unsigned short*)src + e + 8);
    } else {
        const float* p = (const float*)src + e;
        float4 f0 = *(const float4*)p, f1 = *(const float4*)(p + 4);
        float4 f2 = *(const float4*)(p + 8), f3 = *(const float4*)(p + 12);
        u0[0]=f2b(f0.x); u0[1]=f2b(f0.y); u0[2]=f2b(f0.z); u0[3]=f2b(f0.w);
        u0[4]=f2b(f1.x); u0[5]=f2b(f1.y); u0[6]=f2b(f1.z); u0[7]=f2b(f1.w);
        u1[0]=f2b(f2.x); u1[1]=f2b(f2.y); u1[2]=f2b(f2.z); u1[3]=f2b(f2.w);
        u1[4]=f2b(f3.x); u1[5]=f2b(f3.y); u1[6]=f2b(f3.z); u1[7]=f2b(f3.w);
    }
    *(us8*)&T[r][c] = u0;
    *(us8*)&T[r][c + 8] = u1;
    __syncthreads();
    us8 o0, o1;
    #pragma unroll
    for (int i = 0; i < 8; ++i) { o0[i] = T[c + i][r]; o1[i] = T[c + 8 + i][r]; }
    *(us8*)&dst[(size_t)(n0 + r) * K + k0 + c] = o0;
    *(us8*)&dst[(size_t)(n0 + r) * K + k0 + c + 8] = o1;
}

// all-layer (or one-layer) weight transpose. 768 blocks per layer:
// [0,256)=wq/wk/wv/wo (64 tiles each), [256,512)=w1, [512,768)=w2.
__global__ __launch_bounds__(256) void transpose_all(
        const void* wq, const void* wk, const void* wv, const void* wo,
        const void* w1, const void* w2,
        unsigned short* twq, unsigned short* twk, unsigned short* twv, unsigned short* two,
        unsigned short* tw1, unsigned short* tw2,
        int lbase, int slotmul, const int* __restrict__ dtf)
{
    __shared__ __align__(16) unsigned short T[64][72];
    const int bf = dtf[0];
    const int lrel = blockIdx.x / 768;
    const int within = blockIdx.x % 768;
    const int layer = lbase + lrel;
    const int slot = lrel * slotmul;
    const size_t offQ = (size_t)layer * D_ * D_;
    const size_t offF = (size_t)layer * D_ * DFF_;
    const size_t sQ = (size_t)slot * D_ * D_;
    const size_t sF = (size_t)slot * D_ * DFF_;
    if (within < 256) {
        int sel = within >> 6, tile = within & 63;
        const void* s = sel == 0 ? wq : sel == 1 ? wk : sel == 2 ? wv : wo;
        unsigned short* d = (sel == 0 ? twq : sel == 1 ? twk : sel == 2 ? twv : two) + sQ;
        tr_tile(s, offQ, D_, D_, d, (tile & 7) * 64, (tile >> 3) * 64, bf, T);
    } else if (within < 512) {
        int tile = within - 256;   // K=512 (tk=8), N=2048
        tr_tile(w1, offF, D_, DFF_, tw1 + sF, (tile & 7) * 64, (tile >> 3) * 64, bf, T);
    } else {
        int tile = within - 512;   // K=2048 (tk=32), N=512
        tr_tile(w2, offF, DFF_, D_, tw2 + sF, (tile & 31) * 64, (tile >> 5) * 64, bf, T);
    }
}

__global__ __launch_bounds__(256) void transpose_one(const void* src, size_t off,
        int K, int N, unsigned short* dst, const int* __restrict__ dtf)
{
    __shared__ __align__(16) unsigned short T[64][72];
    int tile = blockIdx.x;
    int tk = K / 64;
    tr_tile(src, off, K, N, dst, (tile % tk) * 64, (tile / tk) * 64, dtf[0], T);
}

// ---------------- V transpose: v[b][s][h*DK+dk] -> vt[(b*H+h)][dk][s] ----------------
// grid (S_/64, H_, B_). One 64(s) x 64(dk) tile per block. v is always bf16.
__global__ __launch_bounds__(256) void transpose_vt(
        const unsigned short* __restrict__ v, unsigned short* __restrict__ vt)
{
    __shared__ __align__(16) unsigned short T[64][72];
    tr_tile(v, (size_t)blockIdx.z * S_ * D_ + blockIdx.y * DK_, S_, D_,
            vt + (size_t)(blockIdx.z * H_ + blockIdx.y) * DK_ * S_,
            blockIdx.x * 64, 0, 1, T);
}

// ---------------- MFMA bf16 GEMM, 64x64 tile, BK=64, register prefetch ----------------
// (r2/r6 best-measured config) A[M][K] (bf16 or fp32), Wt[N][K] bf16. 256 thr = 4 waves.
// OUTM: 0=fp32, 1=bf16, 2=dyn(bf flag)
template<bool ABF16, int OUTM, bool RELU, bool ADD>
__device__ __forceinline__ void gemm_core64(
        const void* __restrict__ A, const unsigned short* __restrict__ Wt,
        const void* __restrict__ bias, size_t bOff, const float* __restrict__ Res,
        void* __restrict__ Cout, int M, int N, int K, int bf)
{
    __shared__ __align__(16) unsigned short At[64][72];
    __shared__ __align__(16) unsigned short Bt[64][72];
    const int tid = threadIdx.x;
    const int wave = tid >> 6, lane = tid & 63;
    const int quad = lane >> 4, l16 = lane & 15;
    const int wm = (wave >> 1) * 32, wn = (wave & 1) * 32;
    const int n0 = blockIdx.x * 64, m0 = blockIdx.y * 64;
    const int r = tid >> 2, cb = tid & 3;

    f32x4 acc[2][2];
    #pragma unroll
    for (int mt = 0; mt < 2; ++mt)
        #pragma unroll
        for (int nt = 0; nt < 2; ++nt)
            acc[mt][nt] = (f32x4){0.f, 0.f, 0.f, 0.f};

    us8 aR[2], wR[2];
    float4 aF[4];

    auto loadT = [&](int k0) {
        if (ABF16) {
            const unsigned short* Ap = (const unsigned short*)A + (size_t)(m0 + r) * K + k0;
            aR[0] = *(const us8*)(Ap + cb * 8);
            aR[1] = *(const us8*)(Ap + (cb + 4) * 8);
        } else {
            const float* Ap = (const float*)A + (size_t)(m0 + r) * K + k0;
            aF[0] = *(const float4*)(Ap + cb * 8);
            aF[1] = *(const float4*)(Ap + cb * 8 + 4);
            aF[2] = *(const float4*)(Ap + (cb + 4) * 8);
            aF[3] = *(const float4*)(Ap + (cb + 4) * 8 + 4);
        }
        const unsigned short* Wp = Wt + (size_t)(n0 + r) * K + k0;
        wR[0] = *(const us8*)(Wp + cb * 8);
        wR[1] = *(const us8*)(Wp + (cb + 4) * 8);
    };
    auto storeT = [&]() {
        if (ABF16) {
            *(us8*)&At[r][cb * 8] = aR[0];
            *(us8*)&At[r][(cb + 4) * 8] = aR[1];
        } else {
            us8 u0, u1;
            u0[0]=f2b(aF[0].x); u0[1]=f2b(aF[0].y); u0[2]=f2b(aF[0].z); u0[3]=f2b(aF[0].w);
            u0[4]=f2b(aF[1].x); u0[5]=f2b(aF[1].y); u0[6]=f2b(aF[1].z); u0[7]=f2b(aF[1].w);
            u1[0]=f2b(aF[2].x); u1[1]=f2b(aF[2].y); u1[2]=f2b(aF[2].z); u1[3]=f2b(aF[2].w);
            u1[4]=f2b(aF[3].x); u1[5]=f2b(aF[3].y); u1[6]=f2b(aF[3].z); u1[7]=f2b(aF[3].w);
            *(us8*)&At[r][cb * 8] = u0;
            *(us8*)&At[r][(cb + 4) * 8] = u1;
        }
        *(us8*)&Bt[r][cb * 8] = wR[0];
        *(us8*)&Bt[r][(cb + 4) * 8] = wR[1];
    };

    loadT(0);
    for (int k0 = 0; k0 < K; k0 += 64) {
        __syncthreads();
        storeT();
        __syncthreads();
        if (k0 + 64 < K) loadT(k0 + 64);
        bf16x8 af[2][2], bw[2][2];
        #pragma unroll
        for (int mt = 0; mt < 2; ++mt)
            #pragma unroll
            for (int kh = 0; kh < 2; ++kh)
                af[mt][kh] = *(const bf16x8*)&At[wm + mt * 16 + l16][kh * 32 + quad * 8];
        #pragma unroll
        for (int nt = 0; nt < 2; ++nt)
            #pragma unroll
            for (int kh = 0; kh < 2; ++kh)
                bw[nt][kh] = *(const bf16x8*)&Bt[wn + nt * 16 + l16][kh * 32 + quad * 8];
        #pragma unroll
        for (int mt = 0; mt < 2; ++mt)
            #pragma unroll
            for (int nt = 0; nt < 2; ++nt) {
                acc[mt][nt] = __builtin_amdgcn_mfma_f32_16x16x32_bf16(af[mt][0], bw[nt][0], acc[mt][nt], 0, 0, 0);
                acc[mt][nt] = __builtin_amdgcn_mfma_f32_16x16x32_bf16(af[mt][1], bw[nt][1], acc[mt][nt], 0, 0, 0);
            }
    }

    #pragma unroll
    for (int mt = 0; mt < 2; ++mt) {
        #pragma unroll
        for (int nt = 0; nt < 2; ++nt) {
            int col = n0 + wn + nt * 16 + l16;
            float bv = ldin(bias, bOff + col, bf);
            #pragma unroll
            for (int rr = 0; rr < 4; ++rr) {
                int row = m0 + wm + mt * 16 + quad * 4 + rr;
                float c = acc[mt][nt][rr] + bv;
                if (ADD) c += Res[(size_t)row * N + col];
                if (RELU) c = fmaxf(c, 0.f);
                if (OUTM == 0)      ((float*)Cout)[(size_t)row * N + col] = c;
                else if (OUTM == 1) ((unsigned short*)Cout)[(size_t)row * N + col] = f2b(c);
                else {
                    if (bf) ((unsigned short*)Cout)[(size_t)row * N + col] = f2b(c);
                    else    ((float*)Cout)[(size_t)row * N + col] = c;
                }
            }
        }
    }
}

template<bool ABF16, int OUTM, bool RELU, bool ADD>
__global__ __launch_bounds__(256) void gemm64(
        const void* __restrict__ A, const unsigned short* __restrict__ Wt,
        const void* __restrict__ bias, size_t bOff, const float* __restrict__ Res,
        void* __restrict__ Cout, int M, int N, int K, const int* __restrict__ dtf)
{
    gemm_core64<ABF16, OUTM, RELU, ADD>(A, Wt, bias, bOff, Res, Cout, M, N, K, dtf[0]);
}

// fused QKV: blockIdx.z selects {q,k,v}
__global__ __launch_bounds__(256) void gemm_qkv64(
        const unsigned short* __restrict__ h,
        const unsigned short* twq, const unsigned short* twk, const unsigned short* twv,
        const void* bq, const void* bk, const void* bv, size_t bOff,
        unsigned short* q, unsigned short* k, unsigned short* v,
        const int* __restrict__ dtf)
{
    const int z = blockIdx.z;
    const unsigned short* W = (z == 0) ? twq : (z == 1) ? twk : twv;
    const void* bias = (z == 0) ? bq : (z == 1) ? bk : bv;
    unsigned short* out = (z == 0) ? q : (z == 1) ? k : v;
    gemm_core64<true, 1, false, false>(h, W, bias, bOff, nullptr, out, MROWS, D_, D_, dtf[0]);
}

// ---------------- MFMA flash attention v7: barrier-free per-wave flash ----------------
// Grid (S_/64=32, H, B) = 512 blocks, 256 thr (4 waves). Block qt = 31-bx (heavy first).
// Each wave independently owns 16 q-rows (qt*64 + wave*16 ..+16): Q in regs, K read
// DIRECT from global (L2-resident, 4 MB/layer) as MFMA fragments, V read direct from
// pre-transposed global vt[(b*H+h)][dk][s]. P goes through a per-wave LDS slice
// (same-wave in-order DS, v6 precedent). NO barriers in the k-loop -> waves drift:
// one wave's softmax VALU overlaps another's MFMA/VMEM. Swapped-QK^T softmax (v6).
__global__ __launch_bounds__(256) void attn_flash_v7(
        const unsigned short* __restrict__ qb, const unsigned short* __restrict__ kb,
        const unsigned short* __restrict__ vt, const int* __restrict__ ids,
        unsigned short* __restrict__ ob)
{
    __shared__ __align__(16) unsigned short Ps[4][16][72];
    __shared__ float Msk[S_];
    const int tid = threadIdx.x;
    const int wave = tid >> 6, lane = tid & 63;
    const int quad = lane >> 4, l16 = lane & 15;
    const int qt = 31 - blockIdx.x, h = blockIdx.y, bz = blockIdx.z;
    const size_t hb = (size_t)bz * S_ * D_ + (size_t)h * DK_;
    const unsigned short* vbh = vt + (size_t)(bz * H_ + h) * DK_ * S_;
    const int qrow = qt * 64 + wave * 16 + l16;      // this lane's q-row (softmax domain)

    const int kcols = (qt + 1) * 64;
    for (int i = tid; i < kcols; i += 256)
        Msk[i] = (ids[bz * S_ + i] == 0) ? NEGINF : 0.f;
    __syncthreads();   // the only block-wide barrier

    // Q fragments held in registers for the whole kernel
    bf16x8 aq[2];
    #pragma unroll
    for (int ks = 0; ks < 2; ++ks)
        aq[ks] = *(const bf16x8*)(qb + hb + (size_t)qrow * D_ + ks * 32 + quad * 8);

    f32x4 Oa[4];
    float m_s = NEGINF, l_s = 0.f;
    #pragma unroll
    for (int dt = 0; dt < 4; ++dt) Oa[dt] = (f32x4){0.f, 0.f, 0.f, 0.f};

    #pragma unroll 1
    for (int kt = 0; kt <= qt; ++kt) {
        const bool causal = (kt == qt);
        // ---- S^T strip = mfma(K, Q), K fragments straight from global (L2) ----
        f32x4 sw[4];
        #pragma unroll
        for (int nt = 0; nt < 4; ++nt) sw[nt] = (f32x4){0.f, 0.f, 0.f, 0.f};
        __builtin_amdgcn_s_setprio(1);
        #pragma unroll
        for (int ks = 0; ks < 2; ++ks) {
            #pragma unroll
            for (int nt = 0; nt < 4; ++nt) {
                bf16x8 bk = *(const bf16x8*)(kb + hb +
                        (size_t)(kt * 64 + nt * 16 + l16) * D_ + ks * 32 + quad * 8);
                sw[nt] = __builtin_amdgcn_mfma_f32_16x16x32_bf16(bk, aq[ks], sw[nt], 0, 0, 0);
            }
        }
        __builtin_amdgcn_s_setprio(0);
        // ---- online softmax: lane owns q=qrow with 16 k-values ----
        float sv[4][4];
        float tmax = NEGINF;
        #pragma unroll
        for (int nt = 0; nt < 4; ++nt) {
            f32x4 mskv = *(const f32x4*)&Msk[kt * 64 + nt * 16 + quad * 4];
            #pragma unroll
            for (int rr = 0; rr < 4; ++rr) {
                float s = sw[nt][rr] * 0.125f + mskv[rr];
                if (causal && (nt * 16 + quad * 4 + rr) > (wave * 16 + l16)) s = NEGINF;
                sv[nt][rr] = s;
                tmax = fmaxf(tmax, s);
            }
        }
        tmax = fmaxf(tmax, __shfl_xor(tmax, 16));
        tmax = fmaxf(tmax, __shfl_xor(tmax, 32));
        float mnew = fmaxf(m_s, tmax);
        float alpha = __expf(m_s - mnew);
        float rsum = 0.f;
        #pragma unroll
        for (int nt = 0; nt < 4; ++nt) {
            us4 pk;
            #pragma unroll
            for (int rr = 0; rr < 4; ++rr) {
                float pv = __expf(sv[nt][rr] - mnew);
                rsum += pv;
                pk[rr] = f2b(pv);
            }
            *(us4*)&Ps[wave][l16][nt * 16 + quad * 4] = pk;
        }
        rsum += __shfl_xor(rsum, 16);
        rsum += __shfl_xor(rsum, 32);
        l_s = l_s * alpha + rsum;
        m_s = mnew;
        // rescale Oa rows (row domain q = quad*4 + r)
        #pragma unroll
        for (int r = 0; r < 4; ++r) {
            float ar = __shfl(alpha, quad * 4 + r, 16);
            #pragma unroll
            for (int dt = 0; dt < 4; ++dt) Oa[dt][r] *= ar;
        }
        // ---- O strip += P V, V^T fragments straight from global (L2) ----
        __builtin_amdgcn_s_setprio(1);
        #pragma unroll
        for (int ks = 0; ks < 2; ++ks) {
            bf16x8 ap = *(const bf16x8*)&Ps[wave][l16][ks * 32 + quad * 8];
            #pragma unroll
            for (int dt = 0; dt < 4; ++dt) {
                bf16x8 bv = *(const bf16x8*)(vbh +
                        (size_t)(dt * 16 + l16) * S_ + kt * 64 + ks * 32 + quad * 8);
                Oa[dt] = __builtin_amdgcn_mfma_f32_16x16x32_bf16(ap, bv, Oa[dt], 0, 0, 0);
            }
        }
        __builtin_amdgcn_s_setprio(0);
    }
    // ---- normalize and write bf16 ----
    #pragma unroll
    for (int r = 0; r < 4; ++r) {
        float lr = __shfl(l_s, quad * 4 + r, 16);
        float inv = 1.f / lr;
        int row = qt * 64 + wave * 16 + quad * 4 + r;
        #pragma unroll
        for (int dt = 0; dt < 4; ++dt)
            ob[hb + (size_t)row * D_ + dt * 16 + l16] = f2b(Oa[dt][r] * inv);
    }
}

// ---------------- driver ----------------
extern "C" void kernel_launch(void* const* d_in, const int* in_sizes, int n_in,
                              void* d_out, int out_size, void* d_ws, size_t ws_size,
                              hipStream_t stream)
{
    const int* ids  = (const int*)d_in[0];
    const void* emb = d_in[1];
    const void* wq  = d_in[2];
    const void* bq  = d_in[3];
    const void* wk  = d_in[4];
    const void* bk  = d_in[5];
    const void* wv  = d_in[6];
    const void* bv  = d_in[7];
    const void* wo  = d_in[8];
    const void* bo  = d_in[9];
    const void* ln1w = d_in[10];
    const void* ln1b = d_in[11];
    const void* ln2w = d_in[12];
    const void* ln2b = d_in[13];
    const void* w1  = d_in[14];
    const void* b1  = d_in[15];
    const void* w2  = d_in[16];
    const void* b2  = d_in[17];
    const void* outw = d_in[18];
    const void* outb = d_in[19];

    char* wsp = (char*)d_ws;
    int* dtf = (int*)wsp;
    const size_t NROW = (size_t)MROWS * D_;      // 2097152

    // decide weight-slot count by available workspace
    const size_t fixedBytes = 256
        + 2 * NROW * 4                  // xA, xB fp32
        + 5 * NROW * 2                  // h,q,k,v,o bf16
        + (size_t)MROWS * DFF_ * 2      // ff bf16
        + (size_t)D_ * V_ * 2;          // twout
    const size_t perLayerW = (4 * (size_t)D_ * D_ + 2 * (size_t)D_ * DFF_) * 2;
    const int slots = (ws_size >= fixedBytes + 6 * perLayerW) ? 6 : 1;

    float* xA = (float*)(wsp + 256);
    float* xB = xA + NROW;
    unsigned short* h  = (unsigned short*)(xB + NROW);
    unsigned short* q  = h + NROW;
    unsigned short* k  = q + NROW;
    unsigned short* v  = k + NROW;
    unsigned short* o  = v + NROW;
    unsigned short* ff = o + NROW;                       // MROWS*DFF (also reused as vt)
    unsigned short* twout = ff + (size_t)MROWS * DFF_;
    unsigned short* twq = twout + (size_t)D_ * V_;
    unsigned short* twk = twq + (size_t)slots * D_ * D_;
    unsigned short* twv = twk + (size_t)slots * D_ * D_;
    unsigned short* two = twv + (size_t)slots * D_ * D_;
    unsigned short* tw1 = two + (size_t)slots * D_ * D_;
    unsigned short* tw2 = tw1 + (size_t)slots * D_ * DFF_;
    unsigned short* vt = ff;   // vt[(b*H+h)][dk][s] = 4 MB; ff (16 MB) is dead during attn

    detect_kernel<<<1, 64, 0, stream>>>((const unsigned int*)ln1w, dtf);
    transpose_one<<<(D_/64) * (V_/64), 256, 0, stream>>>(outw, 0, D_, V_, twout, dtf);
    if (slots == 6)
        transpose_all<<<6 * 768, 256, 0, stream>>>(wq, wk, wv, wo, w1, w2,
            twq, twk, twv, two, tw1, tw2, 0, 1, dtf);
    embed_kernel<<<(MROWS * D_) / 256, 256, 0, stream>>>(ids, emb, xA, dtf);

    for (int l = 0; l < L_; ++l) {
        const size_t bOff = (size_t)l * D_;
        const int s = (slots == 6) ? l : 0;
        if (slots == 1)
            transpose_all<<<768, 256, 0, stream>>>(wq, wk, wv, wo, w1, w2,
                twq, twk, twv, two, tw1, tw2, l, 0, dtf);
        const unsigned short* lwq = twq + (size_t)s * D_ * D_;
        const unsigned short* lwk = twk + (size_t)s * D_ * D_;
        const unsigned short* lwv = twv + (size_t)s * D_ * D_;
        const unsigned short* lwo = two + (size_t)s * D_ * D_;
        const unsigned short* lw1 = tw1 + (size_t)s * D_ * DFF_;
        const unsigned short* lw2 = tw2 + (size_t)s * D_ * DFF_;

        ln_kernel<<<MROWS, 256, 0, stream>>>(xA, ln1w, ln1b, bOff, h, dtf);
        gemm_qkv64<<<dim3(D_/64, MROWS/64, 3), 256, 0, stream>>>(
            h, lwq, lwk, lwv, bq, bk, bv, bOff, q, k, v, dtf);
        transpose_vt<<<dim3(S_/64, H_, B_), 256, 0, stream>>>(v, vt);
        attn_flash_v7<<<dim3(S_/64, H_, B_), 256, 0, stream>>>(q, k, vt, ids, o);
        gemm64<true, 0, false, false><<<dim3(D_/64, MROWS/64), 256, 0, stream>>>(
            o, lwo, bo, bOff, nullptr, xB, MROWS, D_, D_, dtf);
        ln_kernel<<<MROWS, 256, 0, stream>>>(xB, ln2w, ln2b, bOff, h, dtf);
        gemm64<true, 1, true, false><<<dim3(DFF_/64, MROWS/64), 256, 0, stream>>>(
            h, lw1, b1, (size_t)l * DFF_, nullptr, ff, MROWS, DFF_, D_, dtf);
        gemm64<true, 0, false, true><<<dim3(D_/64, MROWS/64), 256, 0, stream>>>(
            ff, lw2, b2, bOff, xB, xA, MROWS, D_, DFF_, dtf);
    }
    gemm64<false, 2, false, false><<<dim3(V_/64, MROWS/64), 256, 0, stream>>>(
        xA, twout, outb, 0, nullptr, d_out, MROWS, V_, D_, dtf);
}

// Round 10
// 993.752 us; speedup vs baseline: 1.5859x; 1.5859x over previous
//
#include <hip/hip_runtime.h>
#include <hip/hip_bf16.h>

#define B_ 2
#define S_ 2048
#define V_ 1024
#define D_ 512
#define H_ 8
#define L_ 6
#define DFF_ 2048
#define DK_ 64
#define MROWS (B_*S_)   // 4096
#define NEGINF (-__builtin_inff())

typedef __hip_bfloat16 bf16;
typedef __bf16 bf16x8 __attribute__((ext_vector_type(8)));
typedef float f32x4 __attribute__((ext_vector_type(4)));
typedef unsigned short us8 __attribute__((ext_vector_type(8)));
typedef unsigned short us4 __attribute__((ext_vector_type(4)));
typedef unsigned short us2 __attribute__((ext_vector_type(2)));

__device__ __forceinline__ float bf2f(unsigned short u) {
    return __uint_as_float(((unsigned int)u) << 16);
}
// fp32 -> bf16 round-to-nearest-even
__device__ __forceinline__ unsigned short f2b(float x) {
    unsigned int u = __float_as_uint(x);
    return (unsigned short)((u + 0x7FFFu + ((u >> 16) & 1u)) >> 16);
}
// load element i of a float input that may be fp32 or bf16 (runtime flag bf)
__device__ __forceinline__ float ldin(const void* p, size_t i, int bf) {
    return bf ? bf2f(((const unsigned short*)p)[i]) : ((const float*)p)[i];
}

// ---------------- dtype detector: ln1_w is all ones ----------------
__global__ void detect_kernel(const unsigned int* __restrict__ w, int* __restrict__ flag) {
    if (threadIdx.x == 0) flag[0] = (w[0] == 0x3F800000u) ? 0 : 1;
}

// ---------------- embedding + positional encoding (fp32 out) ----------------
__global__ __launch_bounds__(256) void embed_kernel(const int* __restrict__ ids,
        const void* __restrict__ emb, float* __restrict__ x, const int* __restrict__ dtf)
{
    const int bf = dtf[0];
    int tid = blockIdx.x * 256 + threadIdx.x;   // over B*S*D
    int d = tid % D_;
    int bs = tid / D_;
    int s = bs % S_;
    int id = ids[bs];
    float e = ldin(emb, (size_t)id * D_ + d, bf);
    int i2 = d & ~1;
    float div = expf((float)i2 * (-9.210340371976184f / (float)D_)); // -ln(10000)/D
    float ang = (float)s * div;
    float pe = (d & 1) ? cosf(ang) : sinf(ang);
    x[tid] = e + pe;
}

// ---------------- layernorm: fp32 in, bf16 out (r6-998 proven config) ----------------
__global__ __launch_bounds__(256) void ln_kernel(const float* __restrict__ x,
        const void* __restrict__ w, const void* __restrict__ b, size_t off,
        unsigned short* __restrict__ out, const int* __restrict__ dtf)
{
    const int bf = dtf[0];
    __shared__ float red[256];
    const int row = blockIdx.x;
    const int tid = threadIdx.x;
    const float* xr = x + (size_t)row * D_;
    float v0 = xr[tid], v1 = xr[tid + 256];
    red[tid] = v0 + v1; __syncthreads();
    for (int s = 128; s > 0; s >>= 1) { if (tid < s) red[tid] += red[tid + s]; __syncthreads(); }
    float mu = red[0] * (1.f / D_); __syncthreads();
    float d0 = v0 - mu, d1 = v1 - mu;
    red[tid] = d0 * d0 + d1 * d1; __syncthreads();
    for (int s = 128; s > 0; s >>= 1) { if (tid < s) red[tid] += red[tid + s]; __syncthreads(); }
    float var = red[0] * (1.f / D_);
    float rstd = rsqrtf(var + 1e-5f);
    unsigned short* orow = out + (size_t)row * D_;
    orow[tid]       = f2b(d0 * rstd * ldin(w, off + tid, bf)       + ldin(b, off + tid, bf));
    orow[tid + 256] = f2b(d1 * rstd * ldin(w, off + tid + 256, bf) + ldin(b, off + tid + 256, bf));
}

// ---------------- weight transpose: W[K][N] -> Wt[N][K] bf16, 64x64 LDS tile ----------------
__device__ __forceinline__ void tr_tile(const void* src, size_t off, int K, int N,
        unsigned short* dst, int k0, int n0, int bf, unsigned short (*T)[72])
{
    const int t = threadIdx.x;
    const int r = t >> 2, c = (t & 3) * 16;
    size_t e = off + (size_t)(k0 + r) * N + n0 + c;
    us8 u0, u1;
    if (bf) {
        u0 = *(const us8*)((const unsigned short*)src + e);
        u1 = *(const us8*)((const unsigned short*)src + e + 8);
    } else {
        const float* p = (const float*)src + e;
        float4 f0 = *(const float4*)p, f1 = *(const float4*)(p + 4);
        float4 f2 = *(const float4*)(p + 8), f3 = *(const float4*)(p + 12);
        u0[0]=f2b(f0.x); u0[1]=f2b(f0.y); u0[2]=f2b(f0.z); u0[3]=f2b(f0.w);
        u0[4]=f2b(f1.x); u0[5]=f2b(f1.y); u0[6]=f2b(f1.z); u0[7]=f2b(f1.w);
        u1[0]=f2b(f2.x); u1[1]=f2b(f2.y); u1[2]=f2b(f2.z); u1[3]=f2b(f2.w);
        u1[4]=f2b(f3.x); u1[5]=f2b(f3.y); u1[6]=f2b(f3.z); u1[7]=f2b(f3.w);
    }
    *(us8*)&T[r][c] = u0;
    *(us8*)&T[r][c + 8] = u1;
    __syncthreads();
    us8 o0, o1;
    #pragma unroll
    for (int i = 0; i < 8; ++i) { o0[i] = T[c + i][r]; o1[i] = T[c + 8 + i][r]; }
    *(us8*)&dst[(size_t)(n0 + r) * K + k0 + c] = o0;
    *(us8*)&dst[(size_t)(n0 + r) * K + k0 + c + 8] = o1;
}

// all-layer (or one-layer) weight transpose. 768 blocks per layer:
// [0,256)=wq/wk/wv/wo (64 tiles each), [256,512)=w1, [512,768)=w2.
__global__ __launch_bounds__(256) void transpose_all(
        const void* wq, const void* wk, const void* wv, const void* wo,
        const void* w1, const void* w2,
        unsigned short* twq, unsigned short* twk, unsigned short* twv, unsigned short* two,
        unsigned short* tw1, unsigned short* tw2,
        int lbase, int slotmul, const int* __restrict__ dtf)
{
    __shared__ __align__(16) unsigned short T[64][72];
    const int bf = dtf[0];
    const int lrel = blockIdx.x / 768;
    const int within = blockIdx.x % 768;
    const int layer = lbase + lrel;
    const int slot = lrel * slotmul;
    const size_t offQ = (size_t)layer * D_ * D_;
    const size_t offF = (size_t)layer * D_ * DFF_;
    const size_t sQ = (size_t)slot * D_ * D_;
    const size_t sF = (size_t)slot * D_ * DFF_;
    if (within < 256) {
        int sel = within >> 6, tile = within & 63;
        const void* s = sel == 0 ? wq : sel == 1 ? wk : sel == 2 ? wv : wo;
        unsigned short* d = (sel == 0 ? twq : sel == 1 ? twk : sel == 2 ? twv : two) + sQ;
        tr_tile(s, offQ, D_, D_, d, (tile & 7) * 64, (tile >> 3) * 64, bf, T);
    } else if (within < 512) {
        int tile = within - 256;   // K=512 (tk=8), N=2048
        tr_tile(w1, offF, D_, DFF_, tw1 + sF, (tile & 7) * 64, (tile >> 3) * 64, bf, T);
    } else {
        int tile = within - 512;   // K=2048 (tk=32), N=512
        tr_tile(w2, offF, DFF_, D_, tw2 + sF, (tile & 31) * 64, (tile >> 5) * 64, bf, T);
    }
}

__global__ __launch_bounds__(256) void transpose_one(const void* src, size_t off,
        int K, int N, unsigned short* dst, const int* __restrict__ dtf)
{
    __shared__ __align__(16) unsigned short T[64][72];
    int tile = blockIdx.x;
    int tk = K / 64;
    tr_tile(src, off, K, N, dst, (tile % tk) * 64, (tile / tk) * 64, dtf[0], T);
}

// ---------------- MFMA bf16 GEMM, 64x64 tile, BK=64, register prefetch ----------------
// (r2/r6 best-measured config) A[M][K] (bf16 or fp32), Wt[N][K] bf16. 256 thr = 4 waves.
// OUTM: 0=fp32, 1=bf16, 2=dyn(bf flag)
template<bool ABF16, int OUTM, bool RELU, bool ADD>
__device__ __forceinline__ void gemm_core64(
        const void* __restrict__ A, const unsigned short* __restrict__ Wt,
        const void* __restrict__ bias, size_t bOff, const float* __restrict__ Res,
        void* __restrict__ Cout, int M, int N, int K, int bf)
{
    __shared__ __align__(16) unsigned short At[64][72];
    __shared__ __align__(16) unsigned short Bt[64][72];
    const int tid = threadIdx.x;
    const int wave = tid >> 6, lane = tid & 63;
    const int quad = lane >> 4, l16 = lane & 15;
    const int wm = (wave >> 1) * 32, wn = (wave & 1) * 32;
    const int n0 = blockIdx.x * 64, m0 = blockIdx.y * 64;
    const int r = tid >> 2, cb = tid & 3;

    f32x4 acc[2][2];
    #pragma unroll
    for (int mt = 0; mt < 2; ++mt)
        #pragma unroll
        for (int nt = 0; nt < 2; ++nt)
            acc[mt][nt] = (f32x4){0.f, 0.f, 0.f, 0.f};

    us8 aR[2], wR[2];
    float4 aF[4];

    auto loadT = [&](int k0) {
        if (ABF16) {
            const unsigned short* Ap = (const unsigned short*)A + (size_t)(m0 + r) * K + k0;
            aR[0] = *(const us8*)(Ap + cb * 8);
            aR[1] = *(const us8*)(Ap + (cb + 4) * 8);
        } else {
            const float* Ap = (const float*)A + (size_t)(m0 + r) * K + k0;
            aF[0] = *(const float4*)(Ap + cb * 8);
            aF[1] = *(const float4*)(Ap + cb * 8 + 4);
            aF[2] = *(const float4*)(Ap + (cb + 4) * 8);
            aF[3] = *(const float4*)(Ap + (cb + 4) * 8 + 4);
        }
        const unsigned short* Wp = Wt + (size_t)(n0 + r) * K + k0;
        wR[0] = *(const us8*)(Wp + cb * 8);
        wR[1] = *(const us8*)(Wp + (cb + 4) * 8);
    };
    auto storeT = [&]() {
        if (ABF16) {
            *(us8*)&At[r][cb * 8] = aR[0];
            *(us8*)&At[r][(cb + 4) * 8] = aR[1];
        } else {
            us8 u0, u1;
            u0[0]=f2b(aF[0].x); u0[1]=f2b(aF[0].y); u0[2]=f2b(aF[0].z); u0[3]=f2b(aF[0].w);
            u0[4]=f2b(aF[1].x); u0[5]=f2b(aF[1].y); u0[6]=f2b(aF[1].z); u0[7]=f2b(aF[1].w);
            u1[0]=f2b(aF[2].x); u1[1]=f2b(aF[2].y); u1[2]=f2b(aF[2].z); u1[3]=f2b(aF[2].w);
            u1[4]=f2b(aF[3].x); u1[5]=f2b(aF[3].y); u1[6]=f2b(aF[3].z); u1[7]=f2b(aF[3].w);
            *(us8*)&At[r][cb * 8] = u0;
            *(us8*)&At[r][(cb + 4) * 8] = u1;
        }
        *(us8*)&Bt[r][cb * 8] = wR[0];
        *(us8*)&Bt[r][(cb + 4) * 8] = wR[1];
    };

    loadT(0);
    for (int k0 = 0; k0 < K; k0 += 64) {
        __syncthreads();
        storeT();
        __syncthreads();
        if (k0 + 64 < K) loadT(k0 + 64);
        bf16x8 af[2][2], bw[2][2];
        #pragma unroll
        for (int mt = 0; mt < 2; ++mt)
            #pragma unroll
            for (int kh = 0; kh < 2; ++kh)
                af[mt][kh] = *(const bf16x8*)&At[wm + mt * 16 + l16][kh * 32 + quad * 8];
        #pragma unroll
        for (int nt = 0; nt < 2; ++nt)
            #pragma unroll
            for (int kh = 0; kh < 2; ++kh)
                bw[nt][kh] = *(const bf16x8*)&Bt[wn + nt * 16 + l16][kh * 32 + quad * 8];
        #pragma unroll
        for (int mt = 0; mt < 2; ++mt)
            #pragma unroll
            for (int nt = 0; nt < 2; ++nt) {
                acc[mt][nt] = __builtin_amdgcn_mfma_f32_16x16x32_bf16(af[mt][0], bw[nt][0], acc[mt][nt], 0, 0, 0);
                acc[mt][nt] = __builtin_amdgcn_mfma_f32_16x16x32_bf16(af[mt][1], bw[nt][1], acc[mt][nt], 0, 0, 0);
            }
    }

    #pragma unroll
    for (int mt = 0; mt < 2; ++mt) {
        #pragma unroll
        for (int nt = 0; nt < 2; ++nt) {
            int col = n0 + wn + nt * 16 + l16;
            float bv = ldin(bias, bOff + col, bf);
            #pragma unroll
            for (int rr = 0; rr < 4; ++rr) {
                int row = m0 + wm + mt * 16 + quad * 4 + rr;
                float c = acc[mt][nt][rr] + bv;
                if (ADD) c += Res[(size_t)row * N + col];
                if (RELU) c = fmaxf(c, 0.f);
                if (OUTM == 0)      ((float*)Cout)[(size_t)row * N + col] = c;
                else if (OUTM == 1) ((unsigned short*)Cout)[(size_t)row * N + col] = f2b(c);
                else {
                    if (bf) ((unsigned short*)Cout)[(size_t)row * N + col] = f2b(c);
                    else    ((float*)Cout)[(size_t)row * N + col] = c;
                }
            }
        }
    }
}

template<bool ABF16, int OUTM, bool RELU, bool ADD>
__global__ __launch_bounds__(256) void gemm64(
        const void* __restrict__ A, const unsigned short* __restrict__ Wt,
        const void* __restrict__ bias, size_t bOff, const float* __restrict__ Res,
        void* __restrict__ Cout, int M, int N, int K, const int* __restrict__ dtf)
{
    gemm_core64<ABF16, OUTM, RELU, ADD>(A, Wt, bias, bOff, Res, Cout, M, N, K, dtf[0]);
}

// fused QKV: blockIdx.z selects {q,k,v}
__global__ __launch_bounds__(256) void gemm_qkv64(
        const unsigned short* __restrict__ h,
        const unsigned short* twq, const unsigned short* twk, const unsigned short* twv,
        const void* bq, const void* bk, const void* bv, size_t bOff,
        unsigned short* q, unsigned short* k, unsigned short* v,
        const int* __restrict__ dtf)
{
    const int z = blockIdx.z;
    const unsigned short* W = (z == 0) ? twq : (z == 1) ? twk : twv;
    const void* bias = (z == 0) ? bq : (z == 1) ? bk : bv;
    unsigned short* out = (z == 0) ? q : (z == 1) ? k : v;
    gemm_core64<true, 1, false, false>(h, W, bias, bOff, nullptr, out, MROWS, D_, D_, dtf[0]);
}

// ---------------- MFMA flash attention v6x: v6 + XCD-aware block swizzle ----------------
// 1-D grid of 256 blocks. HW round-robins consecutive block ids across the 8 XCDs;
// decode so XCD x hosts virtual ids [x*32, x*32+32) = exactly 2 (h,bz) groups ->
// each group's 16 q-tile blocks + its 1 MB of K/V stay in ONE XCD's 4 MB L2
// (fixes the 3x HBM over-fetch: FETCH 38 MB vs 12.6 MB input). Bijective on 256;
// balance-neutral (every block runs 17 steps). Compute identical to v6.
__global__ __launch_bounds__(512) void attn_flash_v6(
        const unsigned short* __restrict__ qb, const unsigned short* __restrict__ kb,
        const unsigned short* __restrict__ vb, const int* __restrict__ ids,
        unsigned short* __restrict__ ob)
{
    __shared__ __align__(16) unsigned short Qs[2][64][72];
    __shared__ __align__(16) unsigned short Ks[4][64][72];
    __shared__ __align__(16) unsigned short Vt[4][64][72];
    __shared__ __align__(16) unsigned short Ps[2][64][72];
    __shared__ float Msk[S_];
    const int tid = threadIdx.x;
    const int grp = tid >> 8;
    const int t = tid & 255;
    const int wave = t >> 6, lane = t & 63;
    const int quad = lane >> 4, l16 = lane & 15;
    // XCD swizzle: bid -> (p, h, bz)
    const int bid = blockIdx.x;                  // 0..255
    const int vid = (bid & 7) * 32 + (bid >> 3); // virtual id: XCD-contiguous
    const int p = vid & 15;
    const int g = vid >> 4;                      // (h,bz) group 0..15
    const int h = g & 7, bz = g >> 3;
    const int a = p, bqt = 31 - p;
    const int qt_mine = grp ? bqt : a;
    const size_t hb = (size_t)bz * S_ * D_ + (size_t)h * DK_;
    const int sr = t >> 2, scq = (t & 3) * 16;
    const int pr = t >> 3, cvb = t & 7;

    const int kcols = (bqt + 1) * 64;
    for (int i = tid; i < kcols; i += 512)
        Msk[i] = (ids[bz * S_ + i] == 0) ? NEGINF : 0.f;

    {
        const unsigned short* qp = qb + hb + (size_t)(qt_mine * 64 + sr) * D_ + scq;
        *(us8*)&Qs[grp][sr][scq]     = *(const us8*)qp;
        *(us8*)&Qs[grp][sr][scq + 8] = *(const us8*)(qp + 8);
    }

    us8 kR0, kR1, vA, vB;
    auto loadKV1 = [&](int kt) {
        if (grp == 0) {
            const unsigned short* kp = kb + hb + (size_t)(kt * 64 + sr) * D_ + scq;
            kR0 = *(const us8*)kp;
            kR1 = *(const us8*)(kp + 8);
        } else {
            const unsigned short* vp = vb + hb + (size_t)(kt * 64 + 2 * pr) * D_ + cvb * 8;
            vA = *(const us8*)vp;
            vB = *(const us8*)(vp + D_);
        }
    };
    auto storeKV1 = [&](int buf) {
        if (grp == 0) {
            *(us8*)&Ks[buf][sr][scq]     = kR0;
            *(us8*)&Ks[buf][sr][scq + 8] = kR1;
        } else {
            #pragma unroll
            for (int i = 0; i < 8; ++i) {
                int ii = (i + cvb) & 7;
                us2 u2 = { vA[ii], vB[ii] };
                *(us2*)&Vt[buf][cvb * 8 + ii][2 * pr] = u2;
            }
        }
    };
    auto loadKV2 = [&](int kt) {
        const unsigned short* kp = kb + hb + (size_t)(kt * 64 + sr) * D_ + scq;
        kR0 = *(const us8*)kp;
        kR1 = *(const us8*)(kp + 8);
        const unsigned short* vp = vb + hb + (size_t)(kt * 64 + 2 * pr) * D_ + cvb * 8;
        vA = *(const us8*)vp;
        vB = *(const us8*)(vp + D_);
    };
    auto storeKV2 = [&](int buf) {
        *(us8*)&Ks[buf][sr][scq]     = kR0;
        *(us8*)&Ks[buf][sr][scq + 8] = kR1;
        #pragma unroll
        for (int i = 0; i < 8; ++i) {
            int ii = (i + cvb) & 7;
            us2 u2 = { vA[ii], vB[ii] };
            *(us2*)&Vt[buf][cvb * 8 + ii][2 * pr] = u2;
        }
    };

    f32x4 Oa[4];
    float m_s = NEGINF, l_s = 0.f;
    #pragma unroll
    for (int dt = 0; dt < 4; ++dt) Oa[dt] = (f32x4){0.f, 0.f, 0.f, 0.f};

    auto stepCompute = [&](int qsel, int kt, int buf, bool causal) {
        // ---- S^T strip = mfma(K, Q): row=k-local, col=q=l16 ----
        f32x4 sw[4];
        #pragma unroll
        for (int nt = 0; nt < 4; ++nt) sw[nt] = (f32x4){0.f, 0.f, 0.f, 0.f};
        #pragma unroll
        for (int ks = 0; ks < 2; ++ks) {
            bf16x8 aq = *(const bf16x8*)&Qs[qsel][wave * 16 + l16][ks * 32 + quad * 8];
            #pragma unroll
            for (int nt = 0; nt < 4; ++nt) {
                bf16x8 bk = *(const bf16x8*)&Ks[buf][nt * 16 + l16][ks * 32 + quad * 8];
                sw[nt] = __builtin_amdgcn_mfma_f32_16x16x32_bf16(bk, aq, sw[nt], 0, 0, 0);
            }
        }
        // ---- online softmax, lane owns q = wave*16+l16 with 16 k-values ----
        float sv[4][4];
        float tmax = NEGINF;
        #pragma unroll
        for (int nt = 0; nt < 4; ++nt) {
            f32x4 mskv = *(const f32x4*)&Msk[kt * 64 + nt * 16 + quad * 4];
            #pragma unroll
            for (int rr = 0; rr < 4; ++rr) {
                float s = sw[nt][rr] * 0.125f + mskv[rr];
                if (causal && (nt * 16 + quad * 4 + rr) > (wave * 16 + l16)) s = NEGINF;
                sv[nt][rr] = s;
                tmax = fmaxf(tmax, s);
            }
        }
        tmax = fmaxf(tmax, __shfl_xor(tmax, 16));
        tmax = fmaxf(tmax, __shfl_xor(tmax, 32));
        float mnew = fmaxf(m_s, tmax);
        float alpha = __expf(m_s - mnew);
        float rsum = 0.f;
        #pragma unroll
        for (int nt = 0; nt < 4; ++nt) {
            us4 pk;
            #pragma unroll
            for (int rr = 0; rr < 4; ++rr) {
                float pv = __expf(sv[nt][rr] - mnew);
                rsum += pv;
                pk[rr] = f2b(pv);
            }
            *(us4*)&Ps[grp][wave * 16 + l16][nt * 16 + quad * 4] = pk;
        }
        rsum += __shfl_xor(rsum, 16);
        rsum += __shfl_xor(rsum, 32);
        l_s = l_s * alpha + rsum;
        m_s = mnew;
        // rescale Oa rows (row domain q = quad*4 + r): broadcast alpha from lane l16=row
        #pragma unroll
        for (int r = 0; r < 4; ++r) {
            float ar = __shfl(alpha, quad * 4 + r, 16);
            #pragma unroll
            for (int dt = 0; dt < 4; ++dt) Oa[dt][r] *= ar;
        }
        // ---- O strip += P V ----
        #pragma unroll
        for (int ks = 0; ks < 2; ++ks) {
            bf16x8 ap = *(const bf16x8*)&Ps[grp][wave * 16 + l16][ks * 32 + quad * 8];
            #pragma unroll
            for (int dt = 0; dt < 4; ++dt) {
                bf16x8 bv = *(const bf16x8*)&Vt[buf][dt * 16 + l16][ks * 32 + quad * 8];
                Oa[dt] = __builtin_amdgcn_mfma_f32_16x16x32_bf16(ap, bv, Oa[dt], 0, 0, 0);
            }
        }
    };
    auto writeOut = [&](int qt) {
        #pragma unroll
        for (int r = 0; r < 4; ++r) {
            float lr = __shfl(l_s, quad * 4 + r, 16);
            float inv = 1.f / lr;
            int row = qt * 64 + wave * 16 + quad * 4 + r;
            #pragma unroll
            for (int dt = 0; dt < 4; ++dt)
                ob[hb + (size_t)row * D_ + dt * 16 + l16] = f2b(Oa[dt][r] * inv);
        }
    };

    // ---------------- phase 1: shared tiles kt = 0..a ----------------
    loadKV1(0);
    storeKV1(0);
    if (a >= 1) loadKV1(1);
    __syncthreads();

    #pragma unroll 1
    for (int kt = 0; kt <= a; ++kt) {
        const int cur = kt & 1;
        stepCompute(grp, kt, cur, kt == qt_mine);
        if (kt + 1 <= a) {
            storeKV1(cur ^ 1);
            if (kt + 2 <= a) loadKV1(kt + 2);
            __syncthreads();
        }
    }
    __syncthreads();

    if (grp == 0) {
        writeOut(a);
        m_s = NEGINF; l_s = 0.f;
        #pragma unroll
        for (int dt = 0; dt < 4; ++dt) Oa[dt] = (f32x4){0.f, 0.f, 0.f, 0.f};
    }

    // ---------------- phase 2: split tile b's remaining kt ----------------
    const int nA = 15 - p, nSteps = 16 - p;
    auto activeP2 = [&](int step) { return grp ? (step < nSteps) : (step < nA); };
    auto ktP2 = [&](int step) { return grp ? (16 + step) : (p + 1 + step); };

    if (activeP2(0)) { loadKV2(ktP2(0)); storeKV2(2 * grp); }
    if (activeP2(1)) loadKV2(ktP2(1));
    __syncthreads();

    #pragma unroll 1
    for (int step = 0; step < nSteps; ++step) {
        if (activeP2(step))
            stepCompute(1, ktP2(step), 2 * grp + (step & 1), ktP2(step) == bqt);
        if (step + 1 < nSteps) {
            if (activeP2(step + 1)) storeKV2(2 * grp + ((step + 1) & 1));
            if (step + 2 < nSteps && activeP2(step + 2)) loadKV2(ktP2(step + 2));
        }
        __syncthreads();
    }

    // ---------------- merge group A's tile-b partial into group B ----------------
    float* Ob_ = (float*)&Qs[0][0][0];   // 16 KB (Qs dead)
    float* Ml_ = (float*)&Ps[0][0][0];   // m[64], l[64] (Ps dead)
    if (grp == 0) {
        if (quad == 0) { Ml_[wave * 16 + l16] = m_s; Ml_[64 + wave * 16 + l16] = l_s; }
        #pragma unroll
        for (int dt = 0; dt < 4; ++dt) *(f32x4*)&Ob_[(dt * 256 + t) * 4] = Oa[dt];
    }
    __syncthreads();
    if (grp == 1) {
        float mA = Ml_[wave * 16 + l16], lA = Ml_[64 + wave * 16 + l16];
        float mN = fmaxf(m_s, mA);
        float eB = __expf(m_s - mN), eA = __expf(mA - mN);
        l_s = l_s * eB + lA * eA;
        m_s = mN;
        #pragma unroll
        for (int r = 0; r < 4; ++r) {
            float eBr = __shfl(eB, quad * 4 + r, 16);
            float eAr = __shfl(eA, quad * 4 + r, 16);
            #pragma unroll
            for (int dt = 0; dt < 4; ++dt)
                Oa[dt][r] = Oa[dt][r] * eBr + Ob_[(dt * 256 + t) * 4 + r] * eAr;
        }
        writeOut(bqt);
    }
}

// ---------------- driver ----------------
extern "C" void kernel_launch(void* const* d_in, const int* in_sizes, int n_in,
                              void* d_out, int out_size, void* d_ws, size_t ws_size,
                              hipStream_t stream)
{
    const int* ids  = (const int*)d_in[0];
    const void* emb = d_in[1];
    const void* wq  = d_in[2];
    const void* bq  = d_in[3];
    const void* wk  = d_in[4];
    const void* bk  = d_in[5];
    const void* wv  = d_in[6];
    const void* bv  = d_in[7];
    const void* wo  = d_in[8];
    const void* bo  = d_in[9];
    const void* ln1w = d_in[10];
    const void* ln1b = d_in[11];
    const void* ln2w = d_in[12];
    const void* ln2b = d_in[13];
    const void* w1  = d_in[14];
    const void* b1  = d_in[15];
    const void* w2  = d_in[16];
    const void* b2  = d_in[17];
    const void* outw = d_in[18];
    const void* outb = d_in[19];

    char* wsp = (char*)d_ws;
    int* dtf = (int*)wsp;
    const size_t NROW = (size_t)MROWS * D_;      // 2097152

    // decide weight-slot count by available workspace
    const size_t fixedBytes = 256
        + 2 * NROW * 4                  // xA, xB fp32
        + 5 * NROW * 2                  // h,q,k,v,o bf16
        + (size_t)MROWS * DFF_ * 2      // ff bf16
        + (size_t)D_ * V_ * 2;          // twout
    const size_t perLayerW = (4 * (size_t)D_ * D_ + 2 * (size_t)D_ * DFF_) * 2;
    const int slots = (ws_size >= fixedBytes + 6 * perLayerW) ? 6 : 1;

    float* xA = (float*)(wsp + 256);
    float* xB = xA + NROW;
    unsigned short* h  = (unsigned short*)(xB + NROW);
    unsigned short* q  = h + NROW;
    unsigned short* k  = q + NROW;
    unsigned short* v  = k + NROW;
    unsigned short* o  = v + NROW;
    unsigned short* ff = o + NROW;                       // MROWS*DFF
    unsigned short* twout = ff + (size_t)MROWS * DFF_;
    unsigned short* twq = twout + (size_t)D_ * V_;
    unsigned short* twk = twq + (size_t)slots * D_ * D_;
    unsigned short* twv = twk + (size_t)slots * D_ * D_;
    unsigned short* two = twv + (size_t)slots * D_ * D_;
    unsigned short* tw1 = two + (size_t)slots * D_ * D_;
    unsigned short* tw2 = tw1 + (size_t)slots * D_ * DFF_;

    detect_kernel<<<1, 64, 0, stream>>>((const unsigned int*)ln1w, dtf);
    transpose_one<<<(D_/64) * (V_/64), 256, 0, stream>>>(outw, 0, D_, V_, twout, dtf);
    if (slots == 6)
        transpose_all<<<6 * 768, 256, 0, stream>>>(wq, wk, wv, wo, w1, w2,
            twq, twk, twv, two, tw1, tw2, 0, 1, dtf);
    embed_kernel<<<(MROWS * D_) / 256, 256, 0, stream>>>(ids, emb, xA, dtf);

    for (int l = 0; l < L_; ++l) {
        const size_t bOff = (size_t)l * D_;
        const int s = (slots == 6) ? l : 0;
        if (slots == 1)
            transpose_all<<<768, 256, 0, stream>>>(wq, wk, wv, wo, w1, w2,
                twq, twk, twv, two, tw1, tw2, l, 0, dtf);
        const unsigned short* lwq = twq + (size_t)s * D_ * D_;
        const unsigned short* lwk = twk + (size_t)s * D_ * D_;
        const unsigned short* lwv = twv + (size_t)s * D_ * D_;
        const unsigned short* lwo = two + (size_t)s * D_ * D_;
        const unsigned short* lw1 = tw1 + (size_t)s * D_ * DFF_;
        const unsigned short* lw2 = tw2 + (size_t)s * D_ * DFF_;

        ln_kernel<<<MROWS, 256, 0, stream>>>(xA, ln1w, ln1b, bOff, h, dtf);
        gemm_qkv64<<<dim3(D_/64, MROWS/64, 3), 256, 0, stream>>>(
            h, lwq, lwk, lwv, bq, bk, bv, bOff, q, k, v, dtf);
        attn_flash_v6<<<256, 512, 0, stream>>>(q, k, v, ids, o);
        gemm64<true, 0, false, false><<<dim3(D_/64, MROWS/64), 256, 0, stream>>>(
            o, lwo, bo, bOff, nullptr, xB, MROWS, D_, D_, dtf);
        ln_kernel<<<MROWS, 256, 0, stream>>>(xB, ln2w, ln2b, bOff, h, dtf);
        gemm64<true, 1, true, false><<<dim3(DFF_/64, MROWS/64), 256, 0, stream>>>(
            h, lw1, b1, (size_t)l * DFF_, nullptr, ff, MROWS, DFF_, D_, dtf);
        gemm64<true, 0, false, true><<<dim3(D_/64, MROWS/64), 256, 0, stream>>>(
            ff, lw2, b2, bOff, xB, xA, MROWS, D_, DFF_, dtf);
    }
    gemm64<false, 2, false, false><<<dim3(V_/64, MROWS/64), 256, 0, stream>>>(
        xA, twout, outb, 0, nullptr, d_out, MROWS, V_, D_, dtf);
}

// Round 11
// 984.054 us; speedup vs baseline: 1.6015x; 1.0099x over previous
//
#include <hip/hip_runtime.h>
#include <hip/hip_bf16.h>

#define B_ 2
#define S_ 2048
#define V_ 1024
#define D_ 512
#define H_ 8
#define L_ 6
#define DFF_ 2048
#define DK_ 64
#define MROWS (B_*S_)   // 4096
#define NEGINF (-__builtin_inff())

typedef __hip_bfloat16 bf16;
typedef __bf16 bf16x8 __attribute__((ext_vector_type(8)));
typedef float f32x4 __attribute__((ext_vector_type(4)));
typedef unsigned short us8 __attribute__((ext_vector_type(8)));
typedef unsigned short us4 __attribute__((ext_vector_type(4)));
typedef unsigned short us2 __attribute__((ext_vector_type(2)));

__device__ __forceinline__ float bf2f(unsigned short u) {
    return __uint_as_float(((unsigned int)u) << 16);
}
// fp32 -> bf16 round-to-nearest-even
__device__ __forceinline__ unsigned short f2b(float x) {
    unsigned int u = __float_as_uint(x);
    return (unsigned short)((u + 0x7FFFu + ((u >> 16) & 1u)) >> 16);
}
// load element i of a float input that may be fp32 or bf16 (runtime flag bf)
__device__ __forceinline__ float ldin(const void* p, size_t i, int bf) {
    return bf ? bf2f(((const unsigned short*)p)[i]) : ((const float*)p)[i];
}

// ---------------- dtype detector: ln1_w is all ones ----------------
__global__ void detect_kernel(const unsigned int* __restrict__ w, int* __restrict__ flag) {
    if (threadIdx.x == 0) flag[0] = (w[0] == 0x3F800000u) ? 0 : 1;
}

// ---------------- embedding + positional encoding (fp32 out) ----------------
__global__ __launch_bounds__(256) void embed_kernel(const int* __restrict__ ids,
        const void* __restrict__ emb, float* __restrict__ x, const int* __restrict__ dtf)
{
    const int bf = dtf[0];
    int tid = blockIdx.x * 256 + threadIdx.x;   // over B*S*D
    int d = tid % D_;
    int bs = tid / D_;
    int s = bs % S_;
    int id = ids[bs];
    float e = ldin(emb, (size_t)id * D_ + d, bf);
    int i2 = d & ~1;
    float div = expf((float)i2 * (-9.210340371976184f / (float)D_)); // -ln(10000)/D
    float ang = (float)s * div;
    float pe = (d & 1) ? cosf(ang) : sinf(ang);
    x[tid] = e + pe;
}

// ---------------- layernorm: fp32 in, bf16 out (r6-998 proven config) ----------------
__global__ __launch_bounds__(256) void ln_kernel(const float* __restrict__ x,
        const void* __restrict__ w, const void* __restrict__ b, size_t off,
        unsigned short* __restrict__ out, const int* __restrict__ dtf)
{
    const int bf = dtf[0];
    __shared__ float red[256];
    const int row = blockIdx.x;
    const int tid = threadIdx.x;
    const float* xr = x + (size_t)row * D_;
    float v0 = xr[tid], v1 = xr[tid + 256];
    red[tid] = v0 + v1; __syncthreads();
    for (int s = 128; s > 0; s >>= 1) { if (tid < s) red[tid] += red[tid + s]; __syncthreads(); }
    float mu = red[0] * (1.f / D_); __syncthreads();
    float d0 = v0 - mu, d1 = v1 - mu;
    red[tid] = d0 * d0 + d1 * d1; __syncthreads();
    for (int s = 128; s > 0; s >>= 1) { if (tid < s) red[tid] += red[tid + s]; __syncthreads(); }
    float var = red[0] * (1.f / D_);
    float rstd = rsqrtf(var + 1e-5f);
    unsigned short* orow = out + (size_t)row * D_;
    orow[tid]       = f2b(d0 * rstd * ldin(w, off + tid, bf)       + ldin(b, off + tid, bf));
    orow[tid + 256] = f2b(d1 * rstd * ldin(w, off + tid + 256, bf) + ldin(b, off + tid + 256, bf));
}

// ---------------- weight transpose: W[K][N] -> Wt[N][K] bf16, 64x64 LDS tile ----------------
__device__ __forceinline__ void tr_tile(const void* src, size_t off, int K, int N,
        unsigned short* dst, int k0, int n0, int bf, unsigned short (*T)[72])
{
    const int t = threadIdx.x;
    const int r = t >> 2, c = (t & 3) * 16;
    size_t e = off + (size_t)(k0 + r) * N + n0 + c;
    us8 u0, u1;
    if (bf) {
        u0 = *(const us8*)((const unsigned short*)src + e);
        u1 = *(const us8*)((const unsigned short*)src + e + 8);
    } else {
        const float* p = (const float*)src + e;
        float4 f0 = *(const float4*)p, f1 = *(const float4*)(p + 4);
        float4 f2 = *(const float4*)(p + 8), f3 = *(const float4*)(p + 12);
        u0[0]=f2b(f0.x); u0[1]=f2b(f0.y); u0[2]=f2b(f0.z); u0[3]=f2b(f0.w);
        u0[4]=f2b(f1.x); u0[5]=f2b(f1.y); u0[6]=f2b(f1.z); u0[7]=f2b(f1.w);
        u1[0]=f2b(f2.x); u1[1]=f2b(f2.y); u1[2]=f2b(f2.z); u1[3]=f2b(f2.w);
        u1[4]=f2b(f3.x); u1[5]=f2b(f3.y); u1[6]=f2b(f3.z); u1[7]=f2b(f3.w);
    }
    *(us8*)&T[r][c] = u0;
    *(us8*)&T[r][c + 8] = u1;
    __syncthreads();
    us8 o0, o1;
    #pragma unroll
    for (int i = 0; i < 8; ++i) { o0[i] = T[c + i][r]; o1[i] = T[c + 8 + i][r]; }
    *(us8*)&dst[(size_t)(n0 + r) * K + k0 + c] = o0;
    *(us8*)&dst[(size_t)(n0 + r) * K + k0 + c + 8] = o1;
}

// all-layer (or one-layer) weight transpose. 768 blocks per layer:
// [0,256)=wq/wk/wv/wo (64 tiles each), [256,512)=w1, [512,768)=w2.
__global__ __launch_bounds__(256) void transpose_all(
        const void* wq, const void* wk, const void* wv, const void* wo,
        const void* w1, const void* w2,
        unsigned short* twq, unsigned short* twk, unsigned short* twv, unsigned short* two,
        unsigned short* tw1, unsigned short* tw2,
        int lbase, int slotmul, const int* __restrict__ dtf)
{
    __shared__ __align__(16) unsigned short T[64][72];
    const int bf = dtf[0];
    const int lrel = blockIdx.x / 768;
    const int within = blockIdx.x % 768;
    const int layer = lbase + lrel;
    const int slot = lrel * slotmul;
    const size_t offQ = (size_t)layer * D_ * D_;
    const size_t offF = (size_t)layer * D_ * DFF_;
    const size_t sQ = (size_t)slot * D_ * D_;
    const size_t sF = (size_t)slot * D_ * DFF_;
    if (within < 256) {
        int sel = within >> 6, tile = within & 63;
        const void* s = sel == 0 ? wq : sel == 1 ? wk : sel == 2 ? wv : wo;
        unsigned short* d = (sel == 0 ? twq : sel == 1 ? twk : sel == 2 ? twv : two) + sQ;
        tr_tile(s, offQ, D_, D_, d, (tile & 7) * 64, (tile >> 3) * 64, bf, T);
    } else if (within < 512) {
        int tile = within - 256;   // K=512 (tk=8), N=2048
        tr_tile(w1, offF, D_, DFF_, tw1 + sF, (tile & 7) * 64, (tile >> 3) * 64, bf, T);
    } else {
        int tile = within - 512;   // K=2048 (tk=32), N=512
        tr_tile(w2, offF, DFF_, D_, tw2 + sF, (tile & 31) * 64, (tile >> 5) * 64, bf, T);
    }
}

__global__ __launch_bounds__(256) void transpose_one(const void* src, size_t off,
        int K, int N, unsigned short* dst, const int* __restrict__ dtf)
{
    __shared__ __align__(16) unsigned short T[64][72];
    int tile = blockIdx.x;
    int tk = K / 64;
    tr_tile(src, off, K, N, dst, (tile % tk) * 64, (tile / tk) * 64, dtf[0], T);
}

// ---------------- MFMA bf16 GEMM, 64x64 tile, BK=64, register prefetch ----------------
// (r2/r6 best-measured config) A[M][K] (bf16 or fp32), Wt[N][K] bf16. 256 thr = 4 waves.
// OUTM: 0=fp32, 1=bf16, 2=dyn(bf flag)
template<bool ABF16, int OUTM, bool RELU, bool ADD>
__device__ __forceinline__ void gemm_core64(
        const void* __restrict__ A, const unsigned short* __restrict__ Wt,
        const void* __restrict__ bias, size_t bOff, const float* __restrict__ Res,
        void* __restrict__ Cout, int M, int N, int K, int bf)
{
    __shared__ __align__(16) unsigned short At[64][72];
    __shared__ __align__(16) unsigned short Bt[64][72];
    const int tid = threadIdx.x;
    const int wave = tid >> 6, lane = tid & 63;
    const int quad = lane >> 4, l16 = lane & 15;
    const int wm = (wave >> 1) * 32, wn = (wave & 1) * 32;
    const int n0 = blockIdx.x * 64, m0 = blockIdx.y * 64;
    const int r = tid >> 2, cb = tid & 3;

    f32x4 acc[2][2];
    #pragma unroll
    for (int mt = 0; mt < 2; ++mt)
        #pragma unroll
        for (int nt = 0; nt < 2; ++nt)
            acc[mt][nt] = (f32x4){0.f, 0.f, 0.f, 0.f};

    us8 aR[2], wR[2];
    float4 aF[4];

    auto loadT = [&](int k0) {
        if (ABF16) {
            const unsigned short* Ap = (const unsigned short*)A + (size_t)(m0 + r) * K + k0;
            aR[0] = *(const us8*)(Ap + cb * 8);
            aR[1] = *(const us8*)(Ap + (cb + 4) * 8);
        } else {
            const float* Ap = (const float*)A + (size_t)(m0 + r) * K + k0;
            aF[0] = *(const float4*)(Ap + cb * 8);
            aF[1] = *(const float4*)(Ap + cb * 8 + 4);
            aF[2] = *(const float4*)(Ap + (cb + 4) * 8);
            aF[3] = *(const float4*)(Ap + (cb + 4) * 8 + 4);
        }
        const unsigned short* Wp = Wt + (size_t)(n0 + r) * K + k0;
        wR[0] = *(const us8*)(Wp + cb * 8);
        wR[1] = *(const us8*)(Wp + (cb + 4) * 8);
    };
    auto storeT = [&]() {
        if (ABF16) {
            *(us8*)&At[r][cb * 8] = aR[0];
            *(us8*)&At[r][(cb + 4) * 8] = aR[1];
        } else {
            us8 u0, u1;
            u0[0]=f2b(aF[0].x); u0[1]=f2b(aF[0].y); u0[2]=f2b(aF[0].z); u0[3]=f2b(aF[0].w);
            u0[4]=f2b(aF[1].x); u0[5]=f2b(aF[1].y); u0[6]=f2b(aF[1].z); u0[7]=f2b(aF[1].w);
            u1[0]=f2b(aF[2].x); u1[1]=f2b(aF[2].y); u1[2]=f2b(aF[2].z); u1[3]=f2b(aF[2].w);
            u1[4]=f2b(aF[3].x); u1[5]=f2b(aF[3].y); u1[6]=f2b(aF[3].z); u1[7]=f2b(aF[3].w);
            *(us8*)&At[r][cb * 8] = u0;
            *(us8*)&At[r][(cb + 4) * 8] = u1;
        }
        *(us8*)&Bt[r][cb * 8] = wR[0];
        *(us8*)&Bt[r][(cb + 4) * 8] = wR[1];
    };

    loadT(0);
    for (int k0 = 0; k0 < K; k0 += 64) {
        __syncthreads();
        storeT();
        __syncthreads();
        if (k0 + 64 < K) loadT(k0 + 64);
        bf16x8 af[2][2], bw[2][2];
        #pragma unroll
        for (int mt = 0; mt < 2; ++mt)
            #pragma unroll
            for (int kh = 0; kh < 2; ++kh)
                af[mt][kh] = *(const bf16x8*)&At[wm + mt * 16 + l16][kh * 32 + quad * 8];
        #pragma unroll
        for (int nt = 0; nt < 2; ++nt)
            #pragma unroll
            for (int kh = 0; kh < 2; ++kh)
                bw[nt][kh] = *(const bf16x8*)&Bt[wn + nt * 16 + l16][kh * 32 + quad * 8];
        #pragma unroll
        for (int mt = 0; mt < 2; ++mt)
            #pragma unroll
            for (int nt = 0; nt < 2; ++nt) {
                acc[mt][nt] = __builtin_amdgcn_mfma_f32_16x16x32_bf16(af[mt][0], bw[nt][0], acc[mt][nt], 0, 0, 0);
                acc[mt][nt] = __builtin_amdgcn_mfma_f32_16x16x32_bf16(af[mt][1], bw[nt][1], acc[mt][nt], 0, 0, 0);
            }
    }

    #pragma unroll
    for (int mt = 0; mt < 2; ++mt) {
        #pragma unroll
        for (int nt = 0; nt < 2; ++nt) {
            int col = n0 + wn + nt * 16 + l16;
            float bv = ldin(bias, bOff + col, bf);
            #pragma unroll
            for (int rr = 0; rr < 4; ++rr) {
                int row = m0 + wm + mt * 16 + quad * 4 + rr;
                float c = acc[mt][nt][rr] + bv;
                if (ADD) c += Res[(size_t)row * N + col];
                if (RELU) c = fmaxf(c, 0.f);
                if (OUTM == 0)      ((float*)Cout)[(size_t)row * N + col] = c;
                else if (OUTM == 1) ((unsigned short*)Cout)[(size_t)row * N + col] = f2b(c);
                else {
                    if (bf) ((unsigned short*)Cout)[(size_t)row * N + col] = f2b(c);
                    else    ((float*)Cout)[(size_t)row * N + col] = c;
                }
            }
        }
    }
}

template<bool ABF16, int OUTM, bool RELU, bool ADD>
__global__ __launch_bounds__(256) void gemm64(
        const void* __restrict__ A, const unsigned short* __restrict__ Wt,
        const void* __restrict__ bias, size_t bOff, const float* __restrict__ Res,
        void* __restrict__ Cout, int M, int N, int K, const int* __restrict__ dtf)
{
    gemm_core64<ABF16, OUTM, RELU, ADD>(A, Wt, bias, bOff, Res, Cout, M, N, K, dtf[0]);
}

// fused QKV: blockIdx.z selects {q,k,v}
__global__ __launch_bounds__(256) void gemm_qkv64(
        const unsigned short* __restrict__ h,
        const unsigned short* twq, const unsigned short* twk, const unsigned short* twv,
        const void* bq, const void* bk, const void* bv, size_t bOff,
        unsigned short* q, unsigned short* k, unsigned short* v,
        const int* __restrict__ dtf)
{
    const int z = blockIdx.z;
    const unsigned short* W = (z == 0) ? twq : (z == 1) ? twk : twv;
    const void* bias = (z == 0) ? bq : (z == 1) ? bk : bv;
    unsigned short* out = (z == 0) ? q : (z == 1) ? k : v;
    gemm_core64<true, 1, false, false>(h, W, bias, bOff, nullptr, out, MROWS, D_, D_, dtf[0]);
}

// ---------------- MFMA flash attention v8: v6x + async-STAGE split + defer-max ----------------
// XCD swizzle (r10: FETCH 38->9.3 MB) kept. NEW (T14): per step, ds_write the tile
// loaded LAST step and issue next global loads BEFORE stepCompute, so the barrier's
// vmcnt(0) drain finds the loads already complete (previously issued just before
// the barrier -> full L2 latency stall every step, all 8 waves). NEW (T13):
// defer-max -- when __all(tmax <= m_s + 8), keep old max: skips alpha exp,
// 4 shfl broadcasts, 16 rescale mults (P bounded by e^8, fine in bf16).
__global__ __launch_bounds__(512) void attn_flash_v8(
        const unsigned short* __restrict__ qb, const unsigned short* __restrict__ kb,
        const unsigned short* __restrict__ vb, const int* __restrict__ ids,
        unsigned short* __restrict__ ob)
{
    __shared__ __align__(16) unsigned short Qs[2][64][72];
    __shared__ __align__(16) unsigned short Ks[4][64][72];
    __shared__ __align__(16) unsigned short Vt[4][64][72];
    __shared__ __align__(16) unsigned short Ps[2][64][72];
    __shared__ float Msk[S_];
    const int tid = threadIdx.x;
    const int grp = tid >> 8;
    const int t = tid & 255;
    const int wave = t >> 6, lane = t & 63;
    const int quad = lane >> 4, l16 = lane & 15;
    // XCD swizzle: bid -> (p, h, bz); XCD x hosts 2 full (h,bz) groups
    const int bid = blockIdx.x;                  // 0..255
    const int vid = (bid & 7) * 32 + (bid >> 3); // virtual id: XCD-contiguous
    const int p = vid & 15;
    const int g = vid >> 4;
    const int h = g & 7, bz = g >> 3;
    const int a = p, bqt = 31 - p;
    const int qt_mine = grp ? bqt : a;
    const size_t hb = (size_t)bz * S_ * D_ + (size_t)h * DK_;
    const int sr = t >> 2, scq = (t & 3) * 16;
    const int pr = t >> 3, cvb = t & 7;

    const int kcols = (bqt + 1) * 64;
    for (int i = tid; i < kcols; i += 512)
        Msk[i] = (ids[bz * S_ + i] == 0) ? NEGINF : 0.f;

    {
        const unsigned short* qp = qb + hb + (size_t)(qt_mine * 64 + sr) * D_ + scq;
        *(us8*)&Qs[grp][sr][scq]     = *(const us8*)qp;
        *(us8*)&Qs[grp][sr][scq + 8] = *(const us8*)(qp + 8);
    }

    us8 kR0, kR1, vA, vB;
    auto loadKV1 = [&](int kt) {
        if (grp == 0) {
            const unsigned short* kp = kb + hb + (size_t)(kt * 64 + sr) * D_ + scq;
            kR0 = *(const us8*)kp;
            kR1 = *(const us8*)(kp + 8);
        } else {
            const unsigned short* vp = vb + hb + (size_t)(kt * 64 + 2 * pr) * D_ + cvb * 8;
            vA = *(const us8*)vp;
            vB = *(const us8*)(vp + D_);
        }
    };
    auto storeKV1 = [&](int buf) {
        if (grp == 0) {
            *(us8*)&Ks[buf][sr][scq]     = kR0;
            *(us8*)&Ks[buf][sr][scq + 8] = kR1;
        } else {
            #pragma unroll
            for (int i = 0; i < 8; ++i) {
                int ii = (i + cvb) & 7;
                us2 u2 = { vA[ii], vB[ii] };
                *(us2*)&Vt[buf][cvb * 8 + ii][2 * pr] = u2;
            }
        }
    };
    auto loadKV2 = [&](int kt) {
        const unsigned short* kp = kb + hb + (size_t)(kt * 64 + sr) * D_ + scq;
        kR0 = *(const us8*)kp;
        kR1 = *(const us8*)(kp + 8);
        const unsigned short* vp = vb + hb + (size_t)(kt * 64 + 2 * pr) * D_ + cvb * 8;
        vA = *(const us8*)vp;
        vB = *(const us8*)(vp + D_);
    };
    auto storeKV2 = [&](int buf) {
        *(us8*)&Ks[buf][sr][scq]     = kR0;
        *(us8*)&Ks[buf][sr][scq + 8] = kR1;
        #pragma unroll
        for (int i = 0; i < 8; ++i) {
            int ii = (i + cvb) & 7;
            us2 u2 = { vA[ii], vB[ii] };
            *(us2*)&Vt[buf][cvb * 8 + ii][2 * pr] = u2;
        }
    };

    f32x4 Oa[4];
    float m_s = NEGINF, l_s = 0.f;
    #pragma unroll
    for (int dt = 0; dt < 4; ++dt) Oa[dt] = (f32x4){0.f, 0.f, 0.f, 0.f};

    auto stepCompute = [&](int qsel, int kt, int buf, bool causal) {
        // ---- S^T strip = mfma(K, Q): row=k-local, col=q=l16 ----
        f32x4 sw[4];
        #pragma unroll
        for (int nt = 0; nt < 4; ++nt) sw[nt] = (f32x4){0.f, 0.f, 0.f, 0.f};
        #pragma unroll
        for (int ks = 0; ks < 2; ++ks) {
            bf16x8 aq = *(const bf16x8*)&Qs[qsel][wave * 16 + l16][ks * 32 + quad * 8];
            #pragma unroll
            for (int nt = 0; nt < 4; ++nt) {
                bf16x8 bk = *(const bf16x8*)&Ks[buf][nt * 16 + l16][ks * 32 + quad * 8];
                sw[nt] = __builtin_amdgcn_mfma_f32_16x16x32_bf16(bk, aq, sw[nt], 0, 0, 0);
            }
        }
        // ---- online softmax, lane owns q = wave*16+l16 with 16 k-values ----
        float sv[4][4];
        float tmax = NEGINF;
        #pragma unroll
        for (int nt = 0; nt < 4; ++nt) {
            f32x4 mskv = *(const f32x4*)&Msk[kt * 64 + nt * 16 + quad * 4];
            #pragma unroll
            for (int rr = 0; rr < 4; ++rr) {
                float s = sw[nt][rr] * 0.125f + mskv[rr];
                if (causal && (nt * 16 + quad * 4 + rr) > (wave * 16 + l16)) s = NEGINF;
                sv[nt][rr] = s;
                tmax = fmaxf(tmax, s);
            }
        }
        tmax = fmaxf(tmax, __shfl_xor(tmax, 16));
        tmax = fmaxf(tmax, __shfl_xor(tmax, 32));
        // T13 defer-max: keep old running max when growth <= 8 (wave-uniform vote)
        const bool defer = __all(tmax <= m_s + 8.f);
        float mnew = defer ? m_s : fmaxf(m_s, tmax);
        float rsum = 0.f;
        #pragma unroll
        for (int nt = 0; nt < 4; ++nt) {
            us4 pk;
            #pragma unroll
            for (int rr = 0; rr < 4; ++rr) {
                float pv = __expf(sv[nt][rr] - mnew);
                rsum += pv;
                pk[rr] = f2b(pv);
            }
            *(us4*)&Ps[grp][wave * 16 + l16][nt * 16 + quad * 4] = pk;
        }
        rsum += __shfl_xor(rsum, 16);
        rsum += __shfl_xor(rsum, 32);
        if (defer) {
            l_s += rsum;
        } else {
            float alpha = __expf(m_s - mnew);
            l_s = l_s * alpha + rsum;
            m_s = mnew;
            #pragma unroll
            for (int r = 0; r < 4; ++r) {
                float ar = __shfl(alpha, quad * 4 + r, 16);
                #pragma unroll
                for (int dt = 0; dt < 4; ++dt) Oa[dt][r] *= ar;
            }
        }
        // ---- O strip += P V ----
        #pragma unroll
        for (int ks = 0; ks < 2; ++ks) {
            bf16x8 ap = *(const bf16x8*)&Ps[grp][wave * 16 + l16][ks * 32 + quad * 8];
            #pragma unroll
            for (int dt = 0; dt < 4; ++dt) {
                bf16x8 bv = *(const bf16x8*)&Vt[buf][dt * 16 + l16][ks * 32 + quad * 8];
                Oa[dt] = __builtin_amdgcn_mfma_f32_16x16x32_bf16(ap, bv, Oa[dt], 0, 0, 0);
            }
        }
    };
    auto writeOut = [&](int qt) {
        #pragma unroll
        for (int r = 0; r < 4; ++r) {
            float lr = __shfl(l_s, quad * 4 + r, 16);
            float inv = 1.f / lr;
            int row = qt * 64 + wave * 16 + quad * 4 + r;
            #pragma unroll
            for (int dt = 0; dt < 4; ++dt)
                ob[hb + (size_t)row * D_ + dt * 16 + l16] = f2b(Oa[dt][r] * inv);
        }
    };

    // ---------------- phase 1: shared tiles kt = 0..a ----------------
    // T14 order per step: ds_write(tile kt+1, loaded last step) -> issue loads(kt+2)
    // -> stepCompute(kt) -> barrier (loads land during stepCompute; drain ~free).
    loadKV1(0);
    storeKV1(0);
    if (a >= 1) loadKV1(1);
    __syncthreads();   // Msk, Qs, Ks/Vt[0] visible (one-time prologue drain)

    #pragma unroll 1
    for (int kt = 0; kt <= a; ++kt) {
        const int cur = kt & 1;
        if (kt + 1 <= a) storeKV1(cur ^ 1);   // regs hold tile kt+1 (loaded last step)
        if (kt + 2 <= a) loadKV1(kt + 2);     // in flight across stepCompute
        stepCompute(grp, kt, cur, kt == qt_mine);
        __syncthreads();                      // also serves as post-loop barrier
    }

    if (grp == 0) {
        writeOut(a);
        m_s = NEGINF; l_s = 0.f;
        #pragma unroll
        for (int dt = 0; dt < 4; ++dt) Oa[dt] = (f32x4){0.f, 0.f, 0.f, 0.f};
    }

    // ---------------- phase 2: split tile b's remaining kt ----------------
    const int nA = 15 - p, nSteps = 16 - p;
    auto activeP2 = [&](int step) { return grp ? (step < nSteps) : (step < nA); };
    auto ktP2 = [&](int step) { return grp ? (16 + step) : (p + 1 + step); };

    if (activeP2(0)) { loadKV2(ktP2(0)); storeKV2(2 * grp); }
    if (activeP2(1)) loadKV2(ktP2(1));
    __syncthreads();

    #pragma unroll 1
    for (int step = 0; step < nSteps; ++step) {
        if (step + 1 < nSteps && activeP2(step + 1)) storeKV2(2 * grp + ((step + 1) & 1));
        if (step + 2 < nSteps && activeP2(step + 2)) loadKV2(ktP2(step + 2));
        if (activeP2(step))
            stepCompute(1, ktP2(step), 2 * grp + (step & 1), ktP2(step) == bqt);
        __syncthreads();
    }

    // ---------------- merge group A's tile-b partial into group B ----------------
    float* Ob_ = (float*)&Qs[0][0][0];   // 16 KB (Qs dead)
    float* Ml_ = (float*)&Ps[0][0][0];   // m[64], l[64] (Ps dead)
    if (grp == 0) {
        if (quad == 0) { Ml_[wave * 16 + l16] = m_s; Ml_[64 + wave * 16 + l16] = l_s; }
        #pragma unroll
        for (int dt = 0; dt < 4; ++dt) *(f32x4*)&Ob_[(dt * 256 + t) * 4] = Oa[dt];
    }
    __syncthreads();
    if (grp == 1) {
        float mA = Ml_[wave * 16 + l16], lA = Ml_[64 + wave * 16 + l16];
        float mN = fmaxf(m_s, mA);
        float eB = __expf(m_s - mN), eA = __expf(mA - mN);
        l_s = l_s * eB + lA * eA;
        m_s = mN;
        #pragma unroll
        for (int r = 0; r < 4; ++r) {
            float eBr = __shfl(eB, quad * 4 + r, 16);
            float eAr = __shfl(eA, quad * 4 + r, 16);
            #pragma unroll
            for (int dt = 0; dt < 4; ++dt)
                Oa[dt][r] = Oa[dt][r] * eBr + Ob_[(dt * 256 + t) * 4 + r] * eAr;
        }
        writeOut(bqt);
    }
}

// ---------------- driver ----------------
extern "C" void kernel_launch(void* const* d_in, const int* in_sizes, int n_in,
                              void* d_out, int out_size, void* d_ws, size_t ws_size,
                              hipStream_t stream)
{
    const int* ids  = (const int*)d_in[0];
    const void* emb = d_in[1];
    const void* wq  = d_in[2];
    const void* bq  = d_in[3];
    const void* wk  = d_in[4];
    const void* bk  = d_in[5];
    const void* wv  = d_in[6];
    const void* bv  = d_in[7];
    const void* wo  = d_in[8];
    const void* bo  = d_in[9];
    const void* ln1w = d_in[10];
    const void* ln1b = d_in[11];
    const void* ln2w = d_in[12];
    const void* ln2b = d_in[13];
    const void* w1  = d_in[14];
    const void* b1  = d_in[15];
    const void* w2  = d_in[16];
    const void* b2  = d_in[17];
    const void* outw = d_in[18];
    const void* outb = d_in[19];

    char* wsp = (char*)d_ws;
    int* dtf = (int*)wsp;
    const size_t NROW = (size_t)MROWS * D_;      // 2097152

    // decide weight-slot count by available workspace
    const size_t fixedBytes = 256
        + 2 * NROW * 4                  // xA, xB fp32
        + 5 * NROW * 2                  // h,q,k,v,o bf16
        + (size_t)MROWS * DFF_ * 2      // ff bf16
        + (size_t)D_ * V_ * 2;          // twout
    const size_t perLayerW = (4 * (size_t)D_ * D_ + 2 * (size_t)D_ * DFF_) * 2;
    const int slots = (ws_size >= fixedBytes + 6 * perLayerW) ? 6 : 1;

    float* xA = (float*)(wsp + 256);
    float* xB = xA + NROW;
    unsigned short* h  = (unsigned short*)(xB + NROW);
    unsigned short* q  = h + NROW;
    unsigned short* k  = q + NROW;
    unsigned short* v  = k + NROW;
    unsigned short* o  = v + NROW;
    unsigned short* ff = o + NROW;                       // MROWS*DFF
    unsigned short* twout = ff + (size_t)MROWS * DFF_;
    unsigned short* twq = twout + (size_t)D_ * V_;
    unsigned short* twk = twq + (size_t)slots * D_ * D_;
    unsigned short* twv = twk + (size_t)slots * D_ * D_;
    unsigned short* two = twv + (size_t)slots * D_ * D_;
    unsigned short* tw1 = two + (size_t)slots * D_ * D_;
    unsigned short* tw2 = tw1 + (size_t)slots * D_ * DFF_;

    detect_kernel<<<1, 64, 0, stream>>>((const unsigned int*)ln1w, dtf);
    transpose_one<<<(D_/64) * (V_/64), 256, 0, stream>>>(outw, 0, D_, V_, twout, dtf);
    if (slots == 6)
        transpose_all<<<6 * 768, 256, 0, stream>>>(wq, wk, wv, wo, w1, w2,
            twq, twk, twv, two, tw1, tw2, 0, 1, dtf);
    embed_kernel<<<(MROWS * D_) / 256, 256, 0, stream>>>(ids, emb, xA, dtf);

    for (int l = 0; l < L_; ++l) {
        const size_t bOff = (size_t)l * D_;
        const int s = (slots == 6) ? l : 0;
        if (slots == 1)
            transpose_all<<<768, 256, 0, stream>>>(wq, wk, wv, wo, w1, w2,
                twq, twk, twv, two, tw1, tw2, l, 0, dtf);
        const unsigned short* lwq = twq + (size_t)s * D_ * D_;
        const unsigned short* lwk = twk + (size_t)s * D_ * D_;
        const unsigned short* lwv = twv + (size_t)s * D_ * D_;
        const unsigned short* lwo = two + (size_t)s * D_ * D_;
        const unsigned short* lw1 = tw1 + (size_t)s * D_ * DFF_;
        const unsigned short* lw2 = tw2 + (size_t)s * D_ * DFF_;

        ln_kernel<<<MROWS, 256, 0, stream>>>(xA, ln1w, ln1b, bOff, h, dtf);
        gemm_qkv64<<<dim3(D_/64, MROWS/64, 3), 256, 0, stream>>>(
            h, lwq, lwk, lwv, bq, bk, bv, bOff, q, k, v, dtf);
        attn_flash_v8<<<256, 512, 0, stream>>>(q, k, v, ids, o);
        gemm64<true, 0, false, false><<<dim3(D_/64, MROWS/64), 256, 0, stream>>>(
            o, lwo, bo, bOff, nullptr, xB, MROWS, D_, D_, dtf);
        ln_kernel<<<MROWS, 256, 0, stream>>>(xB, ln2w, ln2b, bOff, h, dtf);
        gemm64<true, 1, true, false><<<dim3(DFF_/64, MROWS/64), 256, 0, stream>>>(
            h, lw1, b1, (size_t)l * DFF_, nullptr, ff, MROWS, DFF_, D_, dtf);
        gemm64<true, 0, false, true><<<dim3(D_/64, MROWS/64), 256, 0, stream>>>(
            ff, lw2, b2, bOff, xB, xA, MROWS, D_, DFF_, dtf);
    }
    gemm64<false, 2, false, false><<<dim3(V_/64, MROWS/64), 256, 0, stream>>>(
        xA, twout, outb, 0, nullptr, d_out, MROWS, V_, D_, dtf);
}

// Round 12
// 966.617 us; speedup vs baseline: 1.6304x; 1.0180x over previous
//
#include <hip/hip_runtime.h>
#include <hip/hip_bf16.h>

#define B_ 2
#define S_ 2048
#define V_ 1024
#define D_ 512
#define H_ 8
#define L_ 6
#define DFF_ 2048
#define DK_ 64
#define MROWS (B_*S_)   // 4096
#define NEGINF (-__builtin_inff())

typedef __hip_bfloat16 bf16;
typedef __bf16 bf16x8 __attribute__((ext_vector_type(8)));
typedef float f32x4 __attribute__((ext_vector_type(4)));
typedef unsigned short us8 __attribute__((ext_vector_type(8)));
typedef unsigned short us4 __attribute__((ext_vector_type(4)));
typedef unsigned short us2 __attribute__((ext_vector_type(2)));

__device__ __forceinline__ float bf2f(unsigned short u) {
    return __uint_as_float(((unsigned int)u) << 16);
}
// fp32 -> bf16 round-to-nearest-even
__device__ __forceinline__ unsigned short f2b(float x) {
    unsigned int u = __float_as_uint(x);
    return (unsigned short)((u + 0x7FFFu + ((u >> 16) & 1u)) >> 16);
}
// load element i of a float input that may be fp32 or bf16 (runtime flag bf)
__device__ __forceinline__ float ldin(const void* p, size_t i, int bf) {
    return bf ? bf2f(((const unsigned short*)p)[i]) : ((const float*)p)[i];
}

// ---------------- dtype detector: ln1_w is all ones ----------------
__global__ void detect_kernel(const unsigned int* __restrict__ w, int* __restrict__ flag) {
    if (threadIdx.x == 0) flag[0] = (w[0] == 0x3F800000u) ? 0 : 1;
}

// ---------------- embedding + positional encoding (fp32 out) ----------------
__global__ __launch_bounds__(256) void embed_kernel(const int* __restrict__ ids,
        const void* __restrict__ emb, float* __restrict__ x, const int* __restrict__ dtf)
{
    const int bf = dtf[0];
    int tid = blockIdx.x * 256 + threadIdx.x;   // over B*S*D
    int d = tid % D_;
    int bs = tid / D_;
    int s = bs % S_;
    int id = ids[bs];
    float e = ldin(emb, (size_t)id * D_ + d, bf);
    int i2 = d & ~1;
    float div = expf((float)i2 * (-9.210340371976184f / (float)D_)); // -ln(10000)/D
    float ang = (float)s * div;
    float pe = (d & 1) ? cosf(ang) : sinf(ang);
    x[tid] = e + pe;
}

// ---------------- layernorm: fp32 in, bf16 out (r6-998 proven config) ----------------
__global__ __launch_bounds__(256) void ln_kernel(const float* __restrict__ x,
        const void* __restrict__ w, const void* __restrict__ b, size_t off,
        unsigned short* __restrict__ out, const int* __restrict__ dtf)
{
    const int bf = dtf[0];
    __shared__ float red[256];
    const int row = blockIdx.x;
    const int tid = threadIdx.x;
    const float* xr = x + (size_t)row * D_;
    float v0 = xr[tid], v1 = xr[tid + 256];
    red[tid] = v0 + v1; __syncthreads();
    for (int s = 128; s > 0; s >>= 1) { if (tid < s) red[tid] += red[tid + s]; __syncthreads(); }
    float mu = red[0] * (1.f / D_); __syncthreads();
    float d0 = v0 - mu, d1 = v1 - mu;
    red[tid] = d0 * d0 + d1 * d1; __syncthreads();
    for (int s = 128; s > 0; s >>= 1) { if (tid < s) red[tid] += red[tid + s]; __syncthreads(); }
    float var = red[0] * (1.f / D_);
    float rstd = rsqrtf(var + 1e-5f);
    unsigned short* orow = out + (size_t)row * D_;
    orow[tid]       = f2b(d0 * rstd * ldin(w, off + tid, bf)       + ldin(b, off + tid, bf));
    orow[tid + 256] = f2b(d1 * rstd * ldin(w, off + tid + 256, bf) + ldin(b, off + tid + 256, bf));
}

// ---------------- weight transpose: W[K][N] -> Wt[N][K] bf16, 64x64 LDS tile ----------------
__device__ __forceinline__ void tr_tile(const void* src, size_t off, int K, int N,
        unsigned short* dst, int k0, int n0, int bf, unsigned short (*T)[72])
{
    const int t = threadIdx.x;
    const int r = t >> 2, c = (t & 3) * 16;
    size_t e = off + (size_t)(k0 + r) * N + n0 + c;
    us8 u0, u1;
    if (bf) {
        u0 = *(const us8*)((const unsigned short*)src + e);
        u1 = *(const us8*)((const unsigned short*)src + e + 8);
    } else {
        const float* p = (const float*)src + e;
        float4 f0 = *(const float4*)p, f1 = *(const float4*)(p + 4);
        float4 f2 = *(const float4*)(p + 8), f3 = *(const float4*)(p + 12);
        u0[0]=f2b(f0.x); u0[1]=f2b(f0.y); u0[2]=f2b(f0.z); u0[3]=f2b(f0.w);
        u0[4]=f2b(f1.x); u0[5]=f2b(f1.y); u0[6]=f2b(f1.z); u0[7]=f2b(f1.w);
        u1[0]=f2b(f2.x); u1[1]=f2b(f2.y); u1[2]=f2b(f2.z); u1[3]=f2b(f2.w);
        u1[4]=f2b(f3.x); u1[5]=f2b(f3.y); u1[6]=f2b(f3.z); u1[7]=f2b(f3.w);
    }
    *(us8*)&T[r][c] = u0;
    *(us8*)&T[r][c + 8] = u1;
    __syncthreads();
    us8 o0, o1;
    #pragma unroll
    for (int i = 0; i < 8; ++i) { o0[i] = T[c + i][r]; o1[i] = T[c + 8 + i][r]; }
    *(us8*)&dst[(size_t)(n0 + r) * K + k0 + c] = o0;
    *(us8*)&dst[(size_t)(n0 + r) * K + k0 + c + 8] = o1;
}

// all-layer (or one-layer) weight transpose. 768 blocks per layer:
// [0,256)=wq/wk/wv/wo (64 tiles each), [256,512)=w1, [512,768)=w2.
__global__ __launch_bounds__(256) void transpose_all(
        const void* wq, const void* wk, const void* wv, const void* wo,
        const void* w1, const void* w2,
        unsigned short* twq, unsigned short* twk, unsigned short* twv, unsigned short* two,
        unsigned short* tw1, unsigned short* tw2,
        int lbase, int slotmul, const int* __restrict__ dtf)
{
    __shared__ __align__(16) unsigned short T[64][72];
    const int bf = dtf[0];
    const int lrel = blockIdx.x / 768;
    const int within = blockIdx.x % 768;
    const int layer = lbase + lrel;
    const int slot = lrel * slotmul;
    const size_t offQ = (size_t)layer * D_ * D_;
    const size_t offF = (size_t)layer * D_ * DFF_;
    const size_t sQ = (size_t)slot * D_ * D_;
    const size_t sF = (size_t)slot * D_ * DFF_;
    if (within < 256) {
        int sel = within >> 6, tile = within & 63;
        const void* s = sel == 0 ? wq : sel == 1 ? wk : sel == 2 ? wv : wo;
        unsigned short* d = (sel == 0 ? twq : sel == 1 ? twk : sel == 2 ? twv : two) + sQ;
        tr_tile(s, offQ, D_, D_, d, (tile & 7) * 64, (tile >> 3) * 64, bf, T);
    } else if (within < 512) {
        int tile = within - 256;   // K=512 (tk=8), N=2048
        tr_tile(w1, offF, D_, DFF_, tw1 + sF, (tile & 7) * 64, (tile >> 3) * 64, bf, T);
    } else {
        int tile = within - 512;   // K=2048 (tk=32), N=512
        tr_tile(w2, offF, DFF_, D_, tw2 + sF, (tile & 31) * 64, (tile >> 5) * 64, bf, T);
    }
}

__global__ __launch_bounds__(256) void transpose_one(const void* src, size_t off,
        int K, int N, unsigned short* dst, const int* __restrict__ dtf)
{
    __shared__ __align__(16) unsigned short T[64][72];
    int tile = blockIdx.x;
    int tk = K / 64;
    tr_tile(src, off, K, N, dst, (tile % tk) * 64, (tile / tk) * 64, dtf[0], T);
}

// ---------------- MFMA bf16 GEMM, 64x64 tile, BK=64, register prefetch ----------------
// (r2/r6 best-measured config) A[M][K] (bf16 or fp32), Wt[N][K] bf16. 256 thr = 4 waves.
// OUTM: 0=fp32, 1=bf16, 2=dyn(bf flag)
template<bool ABF16, int OUTM, bool RELU, bool ADD>
__device__ __forceinline__ void gemm_core64(
        const void* __restrict__ A, const unsigned short* __restrict__ Wt,
        const void* __restrict__ bias, size_t bOff, const float* __restrict__ Res,
        void* __restrict__ Cout, int M, int N, int K, int bf)
{
    __shared__ __align__(16) unsigned short At[64][72];
    __shared__ __align__(16) unsigned short Bt[64][72];
    const int tid = threadIdx.x;
    const int wave = tid >> 6, lane = tid & 63;
    const int quad = lane >> 4, l16 = lane & 15;
    const int wm = (wave >> 1) * 32, wn = (wave & 1) * 32;
    const int n0 = blockIdx.x * 64, m0 = blockIdx.y * 64;
    const int r = tid >> 2, cb = tid & 3;

    f32x4 acc[2][2];
    #pragma unroll
    for (int mt = 0; mt < 2; ++mt)
        #pragma unroll
        for (int nt = 0; nt < 2; ++nt)
            acc[mt][nt] = (f32x4){0.f, 0.f, 0.f, 0.f};

    us8 aR[2], wR[2];
    float4 aF[4];

    auto loadT = [&](int k0) {
        if (ABF16) {
            const unsigned short* Ap = (const unsigned short*)A + (size_t)(m0 + r) * K + k0;
            aR[0] = *(const us8*)(Ap + cb * 8);
            aR[1] = *(const us8*)(Ap + (cb + 4) * 8);
        } else {
            const float* Ap = (const float*)A + (size_t)(m0 + r) * K + k0;
            aF[0] = *(const float4*)(Ap + cb * 8);
            aF[1] = *(const float4*)(Ap + cb * 8 + 4);
            aF[2] = *(const float4*)(Ap + (cb + 4) * 8);
            aF[3] = *(const float4*)(Ap + (cb + 4) * 8 + 4);
        }
        const unsigned short* Wp = Wt + (size_t)(n0 + r) * K + k0;
        wR[0] = *(const us8*)(Wp + cb * 8);
        wR[1] = *(const us8*)(Wp + (cb + 4) * 8);
    };
    auto storeT = [&]() {
        if (ABF16) {
            *(us8*)&At[r][cb * 8] = aR[0];
            *(us8*)&At[r][(cb + 4) * 8] = aR[1];
        } else {
            us8 u0, u1;
            u0[0]=f2b(aF[0].x); u0[1]=f2b(aF[0].y); u0[2]=f2b(aF[0].z); u0[3]=f2b(aF[0].w);
            u0[4]=f2b(aF[1].x); u0[5]=f2b(aF[1].y); u0[6]=f2b(aF[1].z); u0[7]=f2b(aF[1].w);
            u1[0]=f2b(aF[2].x); u1[1]=f2b(aF[2].y); u1[2]=f2b(aF[2].z); u1[3]=f2b(aF[2].w);
            u1[4]=f2b(aF[3].x); u1[5]=f2b(aF[3].y); u1[6]=f2b(aF[3].z); u1[7]=f2b(aF[3].w);
            *(us8*)&At[r][cb * 8] = u0;
            *(us8*)&At[r][(cb + 4) * 8] = u1;
        }
        *(us8*)&Bt[r][cb * 8] = wR[0];
        *(us8*)&Bt[r][(cb + 4) * 8] = wR[1];
    };

    loadT(0);
    for (int k0 = 0; k0 < K; k0 += 64) {
        __syncthreads();
        storeT();
        __syncthreads();
        if (k0 + 64 < K) loadT(k0 + 64);
        bf16x8 af[2][2], bw[2][2];
        #pragma unroll
        for (int mt = 0; mt < 2; ++mt)
            #pragma unroll
            for (int kh = 0; kh < 2; ++kh)
                af[mt][kh] = *(const bf16x8*)&At[wm + mt * 16 + l16][kh * 32 + quad * 8];
        #pragma unroll
        for (int nt = 0; nt < 2; ++nt)
            #pragma unroll
            for (int kh = 0; kh < 2; ++kh)
                bw[nt][kh] = *(const bf16x8*)&Bt[wn + nt * 16 + l16][kh * 32 + quad * 8];
        #pragma unroll
        for (int mt = 0; mt < 2; ++mt)
            #pragma unroll
            for (int nt = 0; nt < 2; ++nt) {
                acc[mt][nt] = __builtin_amdgcn_mfma_f32_16x16x32_bf16(af[mt][0], bw[nt][0], acc[mt][nt], 0, 0, 0);
                acc[mt][nt] = __builtin_amdgcn_mfma_f32_16x16x32_bf16(af[mt][1], bw[nt][1], acc[mt][nt], 0, 0, 0);
            }
    }

    #pragma unroll
    for (int mt = 0; mt < 2; ++mt) {
        #pragma unroll
        for (int nt = 0; nt < 2; ++nt) {
            int col = n0 + wn + nt * 16 + l16;
            float bv = ldin(bias, bOff + col, bf);
            #pragma unroll
            for (int rr = 0; rr < 4; ++rr) {
                int row = m0 + wm + mt * 16 + quad * 4 + rr;
                float c = acc[mt][nt][rr] + bv;
                if (ADD) c += Res[(size_t)row * N + col];
                if (RELU) c = fmaxf(c, 0.f);
                if (OUTM == 0)      ((float*)Cout)[(size_t)row * N + col] = c;
                else if (OUTM == 1) ((unsigned short*)Cout)[(size_t)row * N + col] = f2b(c);
                else {
                    if (bf) ((unsigned short*)Cout)[(size_t)row * N + col] = f2b(c);
                    else    ((float*)Cout)[(size_t)row * N + col] = c;
                }
            }
        }
    }
}

template<bool ABF16, int OUTM, bool RELU, bool ADD>
__global__ __launch_bounds__(256) void gemm64(
        const void* __restrict__ A, const unsigned short* __restrict__ Wt,
        const void* __restrict__ bias, size_t bOff, const float* __restrict__ Res,
        void* __restrict__ Cout, int M, int N, int K, const int* __restrict__ dtf)
{
    gemm_core64<ABF16, OUTM, RELU, ADD>(A, Wt, bias, bOff, Res, Cout, M, N, K, dtf[0]);
}

// fused QKV: blockIdx.z selects {q,k,v}
__global__ __launch_bounds__(256) void gemm_qkv64(
        const unsigned short* __restrict__ h,
        const unsigned short* twq, const unsigned short* twk, const unsigned short* twv,
        const void* bq, const void* bk, const void* bv, size_t bOff,
        unsigned short* q, unsigned short* k, unsigned short* v,
        const int* __restrict__ dtf)
{
    const int z = blockIdx.z;
    const unsigned short* W = (z == 0) ? twq : (z == 1) ? twk : twv;
    const void* bias = (z == 0) ? bq : (z == 1) ? bk : bv;
    unsigned short* out = (z == 0) ? q : (z == 1) ? k : v;
    gemm_core64<true, 1, false, false>(h, W, bias, bOff, nullptr, out, MROWS, D_, D_, dtf[0]);
}

// ---------------- MFMA flash attention v9: 1 q-tile/block, 2 blocks/CU ----------------
// 512 blocks x 256 thr, LDS 62 KB -> 2 blocks/CU co-resident: one block's softmax
// VALU overlaps the other's MFMA/LDS (the m114 mechanism; barriers only couple
// waves WITHIN a block now). Grid decode (1-D, bijective):
//   XCD = bid&7 (HW round-robin assumption), w = bid>>3 = within-XCD arrival.
//   group = XCD*2 + (w&1)  -> each XCD serves 2 (h,bz) groups = 2 MB K/V in its L2 (T1).
//   t = w>>1, qt = t<16 ? 31-t : t-16  -> arrivals j and j+32 (same CU under
//   2-per-CU round-robin) have qt summing to 31 => every CU ~33 steps; heavy-first
//   ordering gives LPT balance even if the mapping assumption is off.
// Per-block loop = v8's proven path: T14 order (ds_write prev, issue next loads,
// THEN compute, then barrier), defer-max (T13), swapped-QK^T softmax. No merge.
__global__ __launch_bounds__(256) void attn_flash_v9(
        const unsigned short* __restrict__ qb, const unsigned short* __restrict__ kb,
        const unsigned short* __restrict__ vb, const int* __restrict__ ids,
        unsigned short* __restrict__ ob)
{
    __shared__ __align__(16) unsigned short Qs[64][72];
    __shared__ __align__(16) unsigned short Ks[2][64][72];
    __shared__ __align__(16) unsigned short Vt[2][64][72];
    __shared__ __align__(16) unsigned short Ps[64][72];
    __shared__ float Msk[S_];
    const int tid = threadIdx.x;
    const int wave = tid >> 6, lane = tid & 63;
    const int quad = lane >> 4, l16 = lane & 15;
    // ---- grid decode ----
    const int bid = blockIdx.x;          // 0..511
    const int w = bid >> 3;              // 0..63 within-XCD arrival
    const int t = w >> 1;                // 0..31
    const int qt = (t < 16) ? (31 - t) : (t - 16);
    const int group = (bid & 7) * 2 + (w & 1);   // 0..15
    const int h = group & 7, bz = group >> 3;
    const size_t hb = (size_t)bz * S_ * D_ + (size_t)h * DK_;
    const int sr = tid >> 2, scq = (tid & 3) * 16;   // K/Q staging
    const int pr = tid >> 3, cvb = tid & 7;          // V staging

    const int kcols = (qt + 1) * 64;
    for (int i = tid; i < kcols; i += 256)
        Msk[i] = (ids[bz * S_ + i] == 0) ? NEGINF : 0.f;

    {   // stage Q tile
        const unsigned short* qp = qb + hb + (size_t)(qt * 64 + sr) * D_ + scq;
        *(us8*)&Qs[sr][scq]     = *(const us8*)qp;
        *(us8*)&Qs[sr][scq + 8] = *(const us8*)(qp + 8);
    }

    us8 kR0, kR1, vA, vB;
    auto loadKV = [&](int kt) {
        const unsigned short* kp = kb + hb + (size_t)(kt * 64 + sr) * D_ + scq;
        kR0 = *(const us8*)kp;
        kR1 = *(const us8*)(kp + 8);
        const unsigned short* vp = vb + hb + (size_t)(kt * 64 + 2 * pr) * D_ + cvb * 8;
        vA = *(const us8*)vp;
        vB = *(const us8*)(vp + D_);
    };
    auto storeKV = [&](int buf) {
        *(us8*)&Ks[buf][sr][scq]     = kR0;
        *(us8*)&Ks[buf][sr][scq + 8] = kR1;
        #pragma unroll
        for (int i = 0; i < 8; ++i) {
            int ii = (i + cvb) & 7;              // rotate -> 2-way max bank alias
            us2 u2 = { vA[ii], vB[ii] };
            *(us2*)&Vt[buf][cvb * 8 + ii][2 * pr] = u2;
        }
    };

    f32x4 Oa[4];
    float m_s = NEGINF, l_s = 0.f;
    #pragma unroll
    for (int dt = 0; dt < 4; ++dt) Oa[dt] = (f32x4){0.f, 0.f, 0.f, 0.f};

    auto stepCompute = [&](int kt, int buf, bool causal) {
        // ---- S^T strip = mfma(K, Q): row=k-local, col=q=l16 ----
        f32x4 sw[4];
        #pragma unroll
        for (int nt = 0; nt < 4; ++nt) sw[nt] = (f32x4){0.f, 0.f, 0.f, 0.f};
        #pragma unroll
        for (int ks = 0; ks < 2; ++ks) {
            bf16x8 aq = *(const bf16x8*)&Qs[wave * 16 + l16][ks * 32 + quad * 8];
            #pragma unroll
            for (int nt = 0; nt < 4; ++nt) {
                bf16x8 bk = *(const bf16x8*)&Ks[buf][nt * 16 + l16][ks * 32 + quad * 8];
                sw[nt] = __builtin_amdgcn_mfma_f32_16x16x32_bf16(bk, aq, sw[nt], 0, 0, 0);
            }
        }
        // ---- online softmax: lane owns q = wave*16+l16 with 16 k-values ----
        float sv[4][4];
        float tmax = NEGINF;
        #pragma unroll
        for (int nt = 0; nt < 4; ++nt) {
            f32x4 mskv = *(const f32x4*)&Msk[kt * 64 + nt * 16 + quad * 4];
            #pragma unroll
            for (int rr = 0; rr < 4; ++rr) {
                float s = sw[nt][rr] * 0.125f + mskv[rr];
                if (causal && (nt * 16 + quad * 4 + rr) > (wave * 16 + l16)) s = NEGINF;
                sv[nt][rr] = s;
                tmax = fmaxf(tmax, s);
            }
        }
        tmax = fmaxf(tmax, __shfl_xor(tmax, 16));
        tmax = fmaxf(tmax, __shfl_xor(tmax, 32));
        const bool defer = __all(tmax <= m_s + 8.f);   // T13
        float mnew = defer ? m_s : fmaxf(m_s, tmax);
        float rsum = 0.f;
        #pragma unroll
        for (int nt = 0; nt < 4; ++nt) {
            us4 pk;
            #pragma unroll
            for (int rr = 0; rr < 4; ++rr) {
                float pv = __expf(sv[nt][rr] - mnew);
                rsum += pv;
                pk[rr] = f2b(pv);
            }
            *(us4*)&Ps[wave * 16 + l16][nt * 16 + quad * 4] = pk;
        }
        rsum += __shfl_xor(rsum, 16);
        rsum += __shfl_xor(rsum, 32);
        if (defer) {
            l_s += rsum;
        } else {
            float alpha = __expf(m_s - mnew);
            l_s = l_s * alpha + rsum;
            m_s = mnew;
            #pragma unroll
            for (int r = 0; r < 4; ++r) {
                float ar = __shfl(alpha, quad * 4 + r, 16);
                #pragma unroll
                for (int dt = 0; dt < 4; ++dt) Oa[dt][r] *= ar;
            }
        }
        // ---- O strip += P V ----
        #pragma unroll
        for (int ks = 0; ks < 2; ++ks) {
            bf16x8 ap = *(const bf16x8*)&Ps[wave * 16 + l16][ks * 32 + quad * 8];
            #pragma unroll
            for (int dt = 0; dt < 4; ++dt) {
                bf16x8 bv = *(const bf16x8*)&Vt[buf][dt * 16 + l16][ks * 32 + quad * 8];
                Oa[dt] = __builtin_amdgcn_mfma_f32_16x16x32_bf16(ap, bv, Oa[dt], 0, 0, 0);
            }
        }
    };

    // ---------------- main loop (T14 order) ----------------
    loadKV(0);
    storeKV(0);
    if (qt >= 1) loadKV(1);
    __syncthreads();   // Msk, Qs, Ks/Vt[0] visible (one-time prologue drain)

    #pragma unroll 1
    for (int kt = 0; kt <= qt; ++kt) {
        const int cur = kt & 1;
        if (kt + 1 <= qt) storeKV(cur ^ 1);   // regs hold tile kt+1 (loaded last step)
        if (kt + 2 <= qt) loadKV(kt + 2);     // in flight across stepCompute
        stepCompute(kt, cur, kt == qt);
        __syncthreads();
    }

    // ---- normalize and write bf16 ----
    #pragma unroll
    for (int r = 0; r < 4; ++r) {
        float lr = __shfl(l_s, quad * 4 + r, 16);
        float inv = 1.f / lr;
        int row = qt * 64 + wave * 16 + quad * 4 + r;
        #pragma unroll
        for (int dt = 0; dt < 4; ++dt)
            ob[hb + (size_t)row * D_ + dt * 16 + l16] = f2b(Oa[dt][r] * inv);
    }
}

// ---------------- driver ----------------
extern "C" void kernel_launch(void* const* d_in, const int* in_sizes, int n_in,
                              void* d_out, int out_size, void* d_ws, size_t ws_size,
                              hipStream_t stream)
{
    const int* ids  = (const int*)d_in[0];
    const void* emb = d_in[1];
    const void* wq  = d_in[2];
    const void* bq  = d_in[3];
    const void* wk  = d_in[4];
    const void* bk  = d_in[5];
    const void* wv  = d_in[6];
    const void* bv  = d_in[7];
    const void* wo  = d_in[8];
    const void* bo  = d_in[9];
    const void* ln1w = d_in[10];
    const void* ln1b = d_in[11];
    const void* ln2w = d_in[12];
    const void* ln2b = d_in[13];
    const void* w1  = d_in[14];
    const void* b1  = d_in[15];
    const void* w2  = d_in[16];
    const void* b2  = d_in[17];
    const void* outw = d_in[18];
    const void* outb = d_in[19];

    char* wsp = (char*)d_ws;
    int* dtf = (int*)wsp;
    const size_t NROW = (size_t)MROWS * D_;      // 2097152

    // decide weight-slot count by available workspace
    const size_t fixedBytes = 256
        + 2 * NROW * 4                  // xA, xB fp32
        + 5 * NROW * 2                  // h,q,k,v,o bf16
        + (size_t)MROWS * DFF_ * 2      // ff bf16
        + (size_t)D_ * V_ * 2;          // twout
    const size_t perLayerW = (4 * (size_t)D_ * D_ + 2 * (size_t)D_ * DFF_) * 2;
    const int slots = (ws_size >= fixedBytes + 6 * perLayerW) ? 6 : 1;

    float* xA = (float*)(wsp + 256);
    float* xB = xA + NROW;
    unsigned short* h  = (unsigned short*)(xB + NROW);
    unsigned short* q  = h + NROW;
    unsigned short* k  = q + NROW;
    unsigned short* v  = k + NROW;
    unsigned short* o  = v + NROW;
    unsigned short* ff = o + NROW;                       // MROWS*DFF
    unsigned short* twout = ff + (size_t)MROWS * DFF_;
    unsigned short* twq = twout + (size_t)D_ * V_;
    unsigned short* twk = twq + (size_t)slots * D_ * D_;
    unsigned short* twv = twk + (size_t)slots * D_ * D_;
    unsigned short* two = twv + (size_t)slots * D_ * D_;
    unsigned short* tw1 = two + (size_t)slots * D_ * D_;
    unsigned short* tw2 = tw1 + (size_t)slots * D_ * DFF_;

    detect_kernel<<<1, 64, 0, stream>>>((const unsigned int*)ln1w, dtf);
    transpose_one<<<(D_/64) * (V_/64), 256, 0, stream>>>(outw, 0, D_, V_, twout, dtf);
    if (slots == 6)
        transpose_all<<<6 * 768, 256, 0, stream>>>(wq, wk, wv, wo, w1, w2,
            twq, twk, twv, two, tw1, tw2, 0, 1, dtf);
    embed_kernel<<<(MROWS * D_) / 256, 256, 0, stream>>>(ids, emb, xA, dtf);

    for (int l = 0; l < L_; ++l) {
        const size_t bOff = (size_t)l * D_;
        const int s = (slots == 6) ? l : 0;
        if (slots == 1)
            transpose_all<<<768, 256, 0, stream>>>(wq, wk, wv, wo, w1, w2,
                twq, twk, twv, two, tw1, tw2, l, 0, dtf);
        const unsigned short* lwq = twq + (size_t)s * D_ * D_;
        const unsigned short* lwk = twk + (size_t)s * D_ * D_;
        const unsigned short* lwv = twv + (size_t)s * D_ * D_;
        const unsigned short* lwo = two + (size_t)s * D_ * D_;
        const unsigned short* lw1 = tw1 + (size_t)s * D_ * DFF_;
        const unsigned short* lw2 = tw2 + (size_t)s * D_ * DFF_;

        ln_kernel<<<MROWS, 256, 0, stream>>>(xA, ln1w, ln1b, bOff, h, dtf);
        gemm_qkv64<<<dim3(D_/64, MROWS/64, 3), 256, 0, stream>>>(
            h, lwq, lwk, lwv, bq, bk, bv, bOff, q, k, v, dtf);
        attn_flash_v9<<<512, 256, 0, stream>>>(q, k, v, ids, o);
        gemm64<true, 0, false, false><<<dim3(D_/64, MROWS/64), 256, 0, stream>>>(
            o, lwo, bo, bOff, nullptr, xB, MROWS, D_, D_, dtf);
        ln_kernel<<<MROWS, 256, 0, stream>>>(xB, ln2w, ln2b, bOff, h, dtf);
        gemm64<true, 1, true, false><<<dim3(DFF_/64, MROWS/64), 256, 0, stream>>>(
            h, lw1, b1, (size_t)l * DFF_, nullptr, ff, MROWS, DFF_, D_, dtf);
        gemm64<true, 0, false, true><<<dim3(D_/64, MROWS/64), 256, 0, stream>>>(
            ff, lw2, b2, bOff, xB, xA, MROWS, D_, DFF_, dtf);
    }
    gemm64<false, 2, false, false><<<dim3(V_/64, MROWS/64), 256, 0, stream>>>(
        xA, twout, outb, 0, nullptr, d_out, MROWS, V_, D_, dtf);
}